// Round 1
// baseline (919.895 us; speedup 1.0000x reference)
//
#include <hip/hip_runtime.h>

// Problem constants
// B=8, C=512, H=W=64, HW=4096, NUM=64, CG=8, NC=19, OUT=512, ICAT=1024

typedef __attribute__((ext_vector_type(8))) unsigned short u16x8;
typedef __attribute__((ext_vector_type(8))) __bf16 bf16x8;
typedef __attribute__((ext_vector_type(4))) float f32x4;

__device__ inline unsigned short f2bf(float f) {
    unsigned int u = __float_as_uint(f);
    u += 0x7fffu + ((u >> 16) & 1u);
    return (unsigned short)(u >> 16);
}

__device__ inline u16x8 zero_u16x8() {
    u16x8 v;
#pragma unroll
    for (int i = 0; i < 8; ++i) v[i] = 0;
    return v;
}

// ---------------------------------------------------------------------------
// Repack bot_w [512][1024][3][3] f32 -> wt[tap][oc][ic] bf16
// ---------------------------------------------------------------------------
__global__ __launch_bounds__(256) void repack_w(const float* __restrict__ w,
                                                unsigned short* __restrict__ wt) {
    int i = blockIdx.x * 256 + threadIdx.x;  // 9*512*1024 = 4718592
    if (i >= 9 * 512 * 1024) return;
    int ic = i & 1023;
    int oc = (i >> 10) & 511;
    int tap = i >> 19;
    float v = w[((size_t)oc * 1024 + ic) * 9 + tap];
    wt[i] = f2bf(v);
}

// ---------------------------------------------------------------------------
// x [8][512][64][64] f32 (NCHW) -> cat[b][y][x][ic] bf16 (NHWC), ic<512 half
// ---------------------------------------------------------------------------
__global__ __launch_bounds__(256) void x_to_cat(const float* __restrict__ x,
                                                unsigned short* __restrict__ cat) {
    __shared__ float t[64][65];
    const int bid = blockIdx.x;  // 8*64*8 = 4096
    const int b = bid >> 9;
    const int y = (bid >> 3) & 63;
    const int c0 = (bid & 7) * 64;
    const int tid = threadIdx.x;
#pragma unroll
    for (int i = 0; i < 16; ++i) {
        int idx = i * 256 + tid;
        int ci = idx >> 6, xx = idx & 63;
        t[ci][xx] = x[((size_t)(b * 512 + c0 + ci)) * 4096 + y * 64 + xx];
    }
    __syncthreads();
#pragma unroll
    for (int i = 0; i < 16; ++i) {
        int idx = i * 256 + tid;
        int xx = idx >> 6, ci = idx & 63;
        cat[((size_t)(b * 4096) + y * 64 + xx) * 1024 + c0 + ci] = f2bf(t[ci][xx]);
    }
}

// ---------------------------------------------------------------------------
// local partials: per (b,n,split) block computes partial local[19][8] over
// 1024 pixels (4 chunks of 256).  part[(bn*4+sp)*152 + k*8+c]
// ---------------------------------------------------------------------------
__global__ __launch_bounds__(256) void local_kernel(
    const float* __restrict__ x, const float* __restrict__ dct,
    const float* __restrict__ w1, const float* __restrict__ gamma,
    const float* __restrict__ beta, const float* __restrict__ w2,
    const float* __restrict__ b2, float* __restrict__ part) {
    __shared__ __align__(16) float fgs[8][260];
    __shared__ __align__(16) float fms[19][260];
    __shared__ float sw1[64], sw2[152], sb2[19], sg[8], sb[8];
    const int bid = blockIdx.x;  // 2048
    const int bn = bid >> 2;
    const int sp = bid & 3;
    const int b = bn >> 6, n = bn & 63;
    const int tid = threadIdx.x;
    if (tid < 64) sw1[tid] = w1[tid];
    if (tid < 152) sw2[tid] = w2[tid];
    if (tid < 19) sb2[tid] = b2[tid];
    if (tid < 8) { sg[tid] = gamma[tid]; sb[tid] = beta[tid]; }
    __syncthreads();
    float accv = 0.f;
    const int kk = tid >> 3, cc = tid & 7;
    for (int ch = 0; ch < 4; ++ch) {
        const int p = (sp * 4 + ch) * 256 + tid;
        float fg[8];
#pragma unroll
        for (int c = 0; c < 8; ++c) {
            fg[c] = x[((size_t)(b * 512 + n * 8 + c)) * 4096 + p] *
                    dct[((size_t)(n * 8 + c)) * 4096 + p];
            fgs[c][tid] = fg[c];
        }
        float h1[8];
#pragma unroll
        for (int d = 0; d < 8; ++d) {
            float s = 0.f;
#pragma unroll
            for (int c = 0; c < 8; ++c) s = fmaf(sw1[d * 8 + c], fg[c], s);
            h1[d] = fmaxf(fmaf(s, sg[d], sb[d]), 0.f);
        }
#pragma unroll
        for (int k = 0; k < 19; ++k) {
            float s = sb2[k];
#pragma unroll
            for (int d = 0; d < 8; ++d) s = fmaf(sw2[k * 8 + d], h1[d], s);
            fms[k][tid] = s;
        }
        __syncthreads();
        if (tid < 152) {
#pragma unroll 8
            for (int p4 = 0; p4 < 256; p4 += 4) {
                const float4 a = *(const float4*)&fms[kk][p4];
                const float4 g4 = *(const float4*)&fgs[cc][p4];
                accv += a.x * g4.x + a.y * g4.y + a.z * g4.z + a.w * g4.w;
            }
        }
        __syncthreads();
    }
    if (tid < 152) part[(size_t)bid * 152 + tid] = accv;
}

// ---------------------------------------------------------------------------
// fuse output (output 1): out1[b][k][p] = sum_n fuse_w[n]*fres_map + fuse_b
// one thread per pixel, loops all 64 groups
// ---------------------------------------------------------------------------
__global__ __launch_bounds__(256) void fuse_kernel(
    const float* __restrict__ x, const float* __restrict__ dct,
    const float* __restrict__ w1, const float* __restrict__ gamma,
    const float* __restrict__ beta, const float* __restrict__ w2,
    const float* __restrict__ b2, const float* __restrict__ fuse_w,
    const float* __restrict__ fuse_b, float* __restrict__ out1) {
    __shared__ float sw1[64], sw2[152], sb2[19], sg[8], sb[8], sfw[64];
    const int tid = threadIdx.x;
    if (tid < 64) { sw1[tid] = w1[tid]; sfw[tid] = fuse_w[tid]; }
    if (tid < 152) sw2[tid] = w2[tid];
    if (tid < 19) sb2[tid] = b2[tid];
    if (tid < 8) { sg[tid] = gamma[tid]; sb[tid] = beta[tid]; }
    __syncthreads();
    const int bp = blockIdx.x;  // 128
    const int b = bp >> 4;
    const int p = (bp & 15) * 256 + tid;
    float facc[19];
#pragma unroll
    for (int k = 0; k < 19; ++k) facc[k] = 0.f;
    for (int n = 0; n < 64; ++n) {
        float fg[8];
#pragma unroll
        for (int c = 0; c < 8; ++c)
            fg[c] = x[((size_t)(b * 512 + n * 8 + c)) * 4096 + p] *
                    dct[((size_t)(n * 8 + c)) * 4096 + p];
        float h1[8];
#pragma unroll
        for (int d = 0; d < 8; ++d) {
            float s = 0.f;
#pragma unroll
            for (int c = 0; c < 8; ++c) s = fmaf(sw1[d * 8 + c], fg[c], s);
            h1[d] = fmaxf(fmaf(s, sg[d], sb[d]), 0.f);
        }
        const float fw = sfw[n];
#pragma unroll
        for (int k = 0; k < 19; ++k) {
            float s = sb2[k];
#pragma unroll
            for (int d = 0; d < 8; ++d) s = fmaf(sw2[k * 8 + d], h1[d], s);
            facc[k] = fmaf(fw, s, facc[k]);
        }
    }
    const float fb = fuse_b[0];
#pragma unroll
    for (int k = 0; k < 19; ++k)
        out1[((size_t)(b * 19) + k) * 4096 + p] = facc[k] + fb;
}

// ---------------------------------------------------------------------------
// GCN: sums 4 partials -> local; g = relu(w1@local + local); local2 = g@w2^T
// one block per batch
// ---------------------------------------------------------------------------
__global__ __launch_bounds__(256) void gcn_kernel(
    const float* __restrict__ part, const float* __restrict__ w1,
    const float* __restrict__ w2, float* __restrict__ local2) {
    __shared__ float L[9728];
    __shared__ float R[9728];
    __shared__ float sw1[4096];
    __shared__ float sw2[64];
    const int b = blockIdx.x;
    const int tid = threadIdx.x;
    for (int i = tid; i < 4096; i += 256) sw1[i] = w1[i];
    if (tid < 64) sw2[tid] = w2[tid];
    for (int i = tid; i < 9728; i += 256) {
        int n = i / 152, t = i - n * 152;
        float s = 0.f;
#pragma unroll
        for (int sp = 0; sp < 4; ++sp)
            s += part[((size_t)((b * 64 + n) * 4 + sp)) * 152 + t];
        L[i] = s;
    }
    __syncthreads();
    for (int i = tid; i < 9728; i += 256) {
        int m = i / 152, t = i - m * 152;
        float g = 0.f;
        for (int n = 0; n < 64; ++n) g = fmaf(sw1[m * 64 + n], L[n * 152 + t], g);
        R[i] = fmaxf(g + L[i], 0.f);
    }
    __syncthreads();
    for (int i = tid; i < 9728; i += 256) {
        int n = i / 152, t = i - n * 152;
        int k = t >> 3, d = t & 7;
        float s = 0.f;
#pragma unroll
        for (int c = 0; c < 8; ++c) s = fmaf(R[n * 152 + k * 8 + c], sw2[d * 8 + c], s);
        local2[(size_t)b * 9728 + i] = s;
    }
}

// ---------------------------------------------------------------------------
// attention: per (b,n): softmax(x^T @ local2^T) @ local2 -> cat upper half bf16
// ---------------------------------------------------------------------------
__global__ __launch_bounds__(256) void attn_kernel(
    const float* __restrict__ x, const float* __restrict__ local2,
    unsigned short* __restrict__ cat) {
    __shared__ float L[152];
    const int bn = blockIdx.x;  // 512
    const int b = bn >> 6, n = bn & 63;
    const int tid = threadIdx.x;
    if (tid < 152) L[tid] = local2[(size_t)bn * 152 + tid];
    __syncthreads();
    for (int i = 0; i < 16; ++i) {
        const int p = i * 256 + tid;
        float xv[8];
#pragma unroll
        for (int c = 0; c < 8; ++c)
            xv[c] = x[((size_t)(b * 512 + n * 8 + c)) * 4096 + p];
        float lg[19];
        float mx = -1e30f;
#pragma unroll
        for (int k = 0; k < 19; ++k) {
            float s = 0.f;
#pragma unroll
            for (int c = 0; c < 8; ++c) s = fmaf(xv[c], L[k * 8 + c], s);
            lg[k] = s;
            mx = fmaxf(mx, s);
        }
        float se = 0.f;
#pragma unroll
        for (int k = 0; k < 19; ++k) {
            lg[k] = __expf(lg[k] - mx);
            se += lg[k];
        }
        const float inv = 1.f / se;
        float ov[8];
#pragma unroll
        for (int c = 0; c < 8; ++c) ov[c] = 0.f;
#pragma unroll
        for (int k = 0; k < 19; ++k) {
#pragma unroll
            for (int c = 0; c < 8; ++c) ov[c] = fmaf(lg[k], L[k * 8 + c], ov[c]);
        }
        u16x8 w;
#pragma unroll
        for (int c = 0; c < 8; ++c) w[c] = f2bf(ov[c] * inv);
        *(u16x8*)(cat + ((size_t)(b * 4096) + p) * 1024 + 512 + n * 8) = w;
    }
}

// ---------------------------------------------------------------------------
// conv 3x3 SAME implicit GEMM, bf16 MFMA 16x16x32, f32 accum.
// Block tile: 128 pixels (2 rows) x 128 oc, K = 9 taps * 1024 ic.
// 4 waves (2x2), each 64x64 via 4x4 fragments.
// ---------------------------------------------------------------------------
__global__ __launch_bounds__(256) void conv_kernel(
    const unsigned short* __restrict__ cat, const unsigned short* __restrict__ wt,
    const float* __restrict__ gamma, const float* __restrict__ beta,
    float* __restrict__ out) {
    __shared__ __align__(16) unsigned short As[128 * 40];
    __shared__ __align__(16) unsigned short Bs[128 * 40];
    const int bid = blockIdx.x;  // 1024
    const int pt = bid >> 2;     // pixel tile 0..255
    const int ot = bid & 3;      // oc tile 0..3
    const int b = pt >> 5;
    const int prow0 = (pt & 31) * 2;  // first image row of this tile
    const int oc0 = ot * 128;
    const int tid = threadIdx.x;
    const int wave = tid >> 6;
    const int lane = tid & 63;
    const int wr = (wave >> 1) * 64;  // wave row offset (pixels)
    const int wc = (wave & 1) * 64;   // wave col offset (oc)
    const int kl = (lane >> 4) * 8;   // k offset within 32-chunk
    const int l16 = lane & 15;
    const int pi0 = tid >> 2;         // staging: first pixel/oc (0..63)
    const int jc = (tid & 3) * 8;     // staging: ic sub-offset

    f32x4 acc[4][4];
#pragma unroll
    for (int m = 0; m < 4; ++m)
#pragma unroll
        for (int n = 0; n < 4; ++n)
#pragma unroll
            for (int j = 0; j < 4; ++j) acc[m][n][j] = 0.f;

    for (int tap = 0; tap < 9; ++tap) {
        const int dy = tap / 3 - 1, dx = tap % 3 - 1;
        int srcp[2];
        bool ok[2];
#pragma unroll
        for (int r = 0; r < 2; ++r) {
            const int yy = prow0 + r + dy;
            const int xx = pi0 + dx;
            ok[r] = ((unsigned)yy < 64u) && ((unsigned)xx < 64u);
            srcp[r] = yy * 64 + xx;
        }
        const unsigned short* wtp = wt + ((size_t)tap * 512 + oc0) * 1024;
        for (int chunk = 0; chunk < 32; ++chunk) {
            const int ic0 = chunk * 32;
#pragma unroll
            for (int r = 0; r < 2; ++r) {
                u16x8 v = zero_u16x8();
                if (ok[r])
                    v = *(const u16x8*)(cat + ((size_t)(b * 4096 + srcp[r])) * 1024 + ic0 + jc);
                *(u16x8*)(As + (pi0 + r * 64) * 40 + jc) = v;
            }
#pragma unroll
            for (int r = 0; r < 2; ++r) {
                u16x8 v = *(const u16x8*)(wtp + (size_t)(pi0 + r * 64) * 1024 + ic0 + jc);
                *(u16x8*)(Bs + (pi0 + r * 64) * 40 + jc) = v;
            }
            __syncthreads();
            bf16x8 af[4], bf[4];
#pragma unroll
            for (int m = 0; m < 4; ++m)
                af[m] = *(const bf16x8*)(As + (wr + m * 16 + l16) * 40 + kl);
#pragma unroll
            for (int n = 0; n < 4; ++n)
                bf[n] = *(const bf16x8*)(Bs + (wc + n * 16 + l16) * 40 + kl);
#pragma unroll
            for (int m = 0; m < 4; ++m)
#pragma unroll
                for (int n = 0; n < 4; ++n)
                    acc[m][n] = __builtin_amdgcn_mfma_f32_16x16x32_bf16(af[m], bf[n], acc[m][n], 0, 0, 0);
            __syncthreads();
        }
    }
    // epilogue: affine + relu, f32 out.  C/D: col(oc)=lane&15, row=(lane>>4)*4+j
    const int pbase = (pt & 31) * 128;
#pragma unroll
    for (int n = 0; n < 4; ++n) {
        const int oc = oc0 + wc + n * 16 + l16;
        const float g = gamma[oc], bb = beta[oc];
#pragma unroll
        for (int m = 0; m < 4; ++m) {
            const int pr = wr + m * 16 + (lane >> 4) * 4;
            float4 o;
            o.x = fmaxf(fmaf(acc[m][n][0], g, bb), 0.f);
            o.y = fmaxf(fmaf(acc[m][n][1], g, bb), 0.f);
            o.z = fmaxf(fmaf(acc[m][n][2], g, bb), 0.f);
            o.w = fmaxf(fmaf(acc[m][n][3], g, bb), 0.f);
            *(float4*)(out + ((size_t)(b * 512 + oc)) * 4096 + pbase + pr) = o;
        }
    }
}

// ---------------------------------------------------------------------------
extern "C" void kernel_launch(void* const* d_in, const int* in_sizes, int n_in,
                              void* d_out, int out_size, void* d_ws, size_t ws_size,
                              hipStream_t stream) {
    const float* x = (const float*)d_in[0];
    const float* dct = (const float*)d_in[1];
    const float* dm_w1 = (const float*)d_in[2];
    const float* dm_g = (const float*)d_in[3];
    const float* dm_b = (const float*)d_in[4];
    const float* dm_w2 = (const float*)d_in[5];
    const float* dm_b2 = (const float*)d_in[6];
    const float* fuse_w = (const float*)d_in[7];
    const float* fuse_b = (const float*)d_in[8];
    const float* gcn_w1 = (const float*)d_in[9];
    const float* gcn_w2 = (const float*)d_in[10];
    const float* bot_w = (const float*)d_in[11];
    const float* bot_g = (const float*)d_in[12];
    const float* bot_b = (const float*)d_in[13];

    float* y = (float*)d_out;
    float* out1 = y + (size_t)8 * 512 * 4096;

    char* ws = (char*)d_ws;
    const size_t CAT_BYTES = (size_t)8 * 4096 * 1024 * 2;     // 67108864
    const size_t WT_BYTES = (size_t)9 * 512 * 1024 * 2;       // 9437184
    const size_t PART_BYTES = (size_t)2048 * 152 * 4;         // 1245184
    const size_t L2_BYTES = (size_t)8 * 9728 * 4;             // 311296
    if (ws_size < CAT_BYTES + WT_BYTES + PART_BYTES + L2_BYTES) return;

    unsigned short* cat = (unsigned short*)ws;
    unsigned short* wt = (unsigned short*)(ws + CAT_BYTES);
    float* part = (float*)(ws + CAT_BYTES + WT_BYTES);
    float* local2 = (float*)(ws + CAT_BYTES + WT_BYTES + PART_BYTES);

    repack_w<<<dim3(18432), dim3(256), 0, stream>>>(bot_w, wt);
    x_to_cat<<<dim3(4096), dim3(256), 0, stream>>>(x, cat);
    local_kernel<<<dim3(2048), dim3(256), 0, stream>>>(x, dct, dm_w1, dm_g, dm_b,
                                                       dm_w2, dm_b2, part);
    fuse_kernel<<<dim3(128), dim3(256), 0, stream>>>(x, dct, dm_w1, dm_g, dm_b,
                                                     dm_w2, dm_b2, fuse_w, fuse_b, out1);
    gcn_kernel<<<dim3(8), dim3(256), 0, stream>>>(part, gcn_w1, gcn_w2, local2);
    attn_kernel<<<dim3(512), dim3(256), 0, stream>>>(x, local2, cat);
    conv_kernel<<<dim3(1024), dim3(256), 0, stream>>>(cat, wt, bot_g, bot_b, y);
}

// Round 2
// 617.707 us; speedup vs baseline: 1.4892x; 1.4892x over previous
//
#include <hip/hip_runtime.h>

// Problem constants
// B=8, C=512, H=W=64, HW=4096, NUM=64, CG=8, NC=19, OUT=512, ICAT=1024

typedef __attribute__((ext_vector_type(8))) unsigned short u16x8;
typedef __attribute__((ext_vector_type(8))) __bf16 bf16x8;
typedef __attribute__((ext_vector_type(4))) float f32x4;

__device__ inline unsigned short f2bf(float f) {
    unsigned int u = __float_as_uint(f);
    u += 0x7fffu + ((u >> 16) & 1u);
    return (unsigned short)(u >> 16);
}

__device__ __forceinline__ void gload16(unsigned short* lds, const unsigned short* g) {
    __builtin_amdgcn_global_load_lds(
        (const __attribute__((address_space(1))) unsigned int*)g,
        (__attribute__((address_space(3))) unsigned int*)lds, 16, 0, 0);
}

// ---------------------------------------------------------------------------
// Repack bot_w [512][1024][3][3] f32 -> wt[tap][oc][ic] bf16
// ---------------------------------------------------------------------------
__global__ __launch_bounds__(256) void repack_w(const float* __restrict__ w,
                                                unsigned short* __restrict__ wt) {
    int i = blockIdx.x * 256 + threadIdx.x;  // 9*512*1024 = 4718592
    if (i >= 9 * 512 * 1024) return;
    int ic = i & 1023;
    int oc = (i >> 10) & 511;
    int tap = i >> 19;
    float v = w[((size_t)oc * 1024 + ic) * 9 + tap];
    wt[i] = f2bf(v);
}

// ---------------------------------------------------------------------------
// x [8][512][64][64] f32 (NCHW) -> cat[b][p][ic] bf16 (NHWC), ic<512 half
// ---------------------------------------------------------------------------
__global__ __launch_bounds__(256) void x_to_cat(const float* __restrict__ x,
                                                unsigned short* __restrict__ cat) {
    __shared__ float t[64][65];
    const int bid = blockIdx.x;  // 8*64*8 = 4096
    const int b = bid >> 9;
    const int y = (bid >> 3) & 63;
    const int c0 = (bid & 7) * 64;
    const int tid = threadIdx.x;
#pragma unroll
    for (int i = 0; i < 16; ++i) {
        int idx = i * 256 + tid;
        int ci = idx >> 6, xx = idx & 63;
        t[ci][xx] = x[((size_t)(b * 512 + c0 + ci)) * 4096 + y * 64 + xx];
    }
    __syncthreads();
#pragma unroll
    for (int i = 0; i < 16; ++i) {
        int idx = i * 256 + tid;
        int xx = idx >> 6, ci = idx & 63;
        cat[((size_t)(b * 4096) + y * 64 + xx) * 1024 + c0 + ci] = f2bf(t[ci][xx]);
    }
}

// ---------------------------------------------------------------------------
// local partials: per (b,n,split) block computes partial local[19][8] over
// 1024 pixels (4 chunks of 256).  part[(bn*4+sp)*152 + k*8+c]
// ---------------------------------------------------------------------------
__global__ __launch_bounds__(256) void local_kernel(
    const float* __restrict__ x, const float* __restrict__ dct,
    const float* __restrict__ w1, const float* __restrict__ gamma,
    const float* __restrict__ beta, const float* __restrict__ w2,
    const float* __restrict__ b2, float* __restrict__ part) {
    __shared__ __align__(16) float fgs[8][260];
    __shared__ __align__(16) float fms[19][260];
    __shared__ float sw1[64], sw2[152], sb2[19], sg[8], sb[8];
    const int bid = blockIdx.x;  // 2048
    const int bn = bid >> 2;
    const int sp = bid & 3;
    const int b = bn >> 6, n = bn & 63;
    const int tid = threadIdx.x;
    if (tid < 64) sw1[tid] = w1[tid];
    if (tid < 152) sw2[tid] = w2[tid];
    if (tid < 19) sb2[tid] = b2[tid];
    if (tid < 8) { sg[tid] = gamma[tid]; sb[tid] = beta[tid]; }
    __syncthreads();
    float accv = 0.f;
    const int kk = tid >> 3, cc = tid & 7;
    for (int ch = 0; ch < 4; ++ch) {
        const int p = (sp * 4 + ch) * 256 + tid;
        float fg[8];
#pragma unroll
        for (int c = 0; c < 8; ++c) {
            fg[c] = x[((size_t)(b * 512 + n * 8 + c)) * 4096 + p] *
                    dct[((size_t)(n * 8 + c)) * 4096 + p];
            fgs[c][tid] = fg[c];
        }
        float h1[8];
#pragma unroll
        for (int d = 0; d < 8; ++d) {
            float s = 0.f;
#pragma unroll
            for (int c = 0; c < 8; ++c) s = fmaf(sw1[d * 8 + c], fg[c], s);
            h1[d] = fmaxf(fmaf(s, sg[d], sb[d]), 0.f);
        }
#pragma unroll
        for (int k = 0; k < 19; ++k) {
            float s = sb2[k];
#pragma unroll
            for (int d = 0; d < 8; ++d) s = fmaf(sw2[k * 8 + d], h1[d], s);
            fms[k][tid] = s;
        }
        __syncthreads();
        if (tid < 152) {
#pragma unroll 8
            for (int p4 = 0; p4 < 256; p4 += 4) {
                const float4 a = *(const float4*)&fms[kk][p4];
                const float4 g4 = *(const float4*)&fgs[cc][p4];
                accv += a.x * g4.x + a.y * g4.y + a.z * g4.z + a.w * g4.w;
            }
        }
        __syncthreads();
    }
    if (tid < 152) part[(size_t)bid * 152 + tid] = accv;
}

// ---------------------------------------------------------------------------
// fuse partial: split over 8 group-chunks for occupancy.
// fpart[sp][b][k][p] at linear ((sp*8+b)*19+k)*4096+p
// ---------------------------------------------------------------------------
__global__ __launch_bounds__(256) void fuse_part(
    const float* __restrict__ x, const float* __restrict__ dct,
    const float* __restrict__ w1, const float* __restrict__ gamma,
    const float* __restrict__ beta, const float* __restrict__ w2,
    const float* __restrict__ b2, const float* __restrict__ fuse_w,
    float* __restrict__ fpart) {
    __shared__ float sw1[64], sw2[152], sb2[19], sg[8], sb[8], sfw[64];
    const int tid = threadIdx.x;
    if (tid < 64) { sw1[tid] = w1[tid]; sfw[tid] = fuse_w[tid]; }
    if (tid < 152) sw2[tid] = w2[tid];
    if (tid < 19) sb2[tid] = b2[tid];
    if (tid < 8) { sg[tid] = gamma[tid]; sb[tid] = beta[tid]; }
    __syncthreads();
    const int bid = blockIdx.x;  // 1024
    const int sp = bid >> 7;
    const int rest = bid & 127;
    const int b = rest >> 4;
    const int p = (rest & 15) * 256 + tid;
    float facc[19];
#pragma unroll
    for (int k = 0; k < 19; ++k) facc[k] = 0.f;
    for (int nn = 0; nn < 8; ++nn) {
        const int n = sp * 8 + nn;
        float fg[8];
#pragma unroll
        for (int c = 0; c < 8; ++c)
            fg[c] = x[((size_t)(b * 512 + n * 8 + c)) * 4096 + p] *
                    dct[((size_t)(n * 8 + c)) * 4096 + p];
        float h1[8];
#pragma unroll
        for (int d = 0; d < 8; ++d) {
            float s = 0.f;
#pragma unroll
            for (int c = 0; c < 8; ++c) s = fmaf(sw1[d * 8 + c], fg[c], s);
            h1[d] = fmaxf(fmaf(s, sg[d], sb[d]), 0.f);
        }
        const float fw = sfw[n];
#pragma unroll
        for (int k = 0; k < 19; ++k) {
            float s = sb2[k];
#pragma unroll
            for (int d = 0; d < 8; ++d) s = fmaf(sw2[k * 8 + d], h1[d], s);
            facc[k] = fmaf(fw, s, facc[k]);
        }
    }
#pragma unroll
    for (int k = 0; k < 19; ++k)
        fpart[((size_t)(sp * 8 + b) * 19 + k) * 4096 + p] = facc[k];
}

__global__ __launch_bounds__(256) void fuse_reduce(
    const float* __restrict__ fpart, const float* __restrict__ fuse_b,
    float* __restrict__ out1) {
    const int i = blockIdx.x * 256 + threadIdx.x;  // 622592 total
    float s = fuse_b[0];
#pragma unroll
    for (int sp = 0; sp < 8; ++sp) s += fpart[(size_t)sp * 622592 + i];
    out1[i] = s;
}

// ---------------------------------------------------------------------------
// GCN: sums 4 partials -> local; g = relu(w1@local + local); local2 = g@w2^T
// ---------------------------------------------------------------------------
__global__ __launch_bounds__(256) void gcn_kernel(
    const float* __restrict__ part, const float* __restrict__ w1,
    const float* __restrict__ w2, float* __restrict__ local2) {
    __shared__ float L[9728];
    __shared__ float R[9728];
    __shared__ float sw1[4096];
    __shared__ float sw2[64];
    const int b = blockIdx.x;
    const int tid = threadIdx.x;
    for (int i = tid; i < 4096; i += 256) sw1[i] = w1[i];
    if (tid < 64) sw2[tid] = w2[tid];
    for (int i = tid; i < 9728; i += 256) {
        int n = i / 152, t = i - n * 152;
        float s = 0.f;
#pragma unroll
        for (int sp = 0; sp < 4; ++sp)
            s += part[((size_t)((b * 64 + n) * 4 + sp)) * 152 + t];
        L[i] = s;
    }
    __syncthreads();
    for (int i = tid; i < 9728; i += 256) {
        int m = i / 152, t = i - m * 152;
        float g = 0.f;
        for (int n = 0; n < 64; ++n) g = fmaf(sw1[m * 64 + n], L[n * 152 + t], g);
        R[i] = fmaxf(g + L[i], 0.f);
    }
    __syncthreads();
    for (int i = tid; i < 9728; i += 256) {
        int n = i / 152, t = i - n * 152;
        int k = t >> 3, d = t & 7;
        float s = 0.f;
#pragma unroll
        for (int c = 0; c < 8; ++c) s = fmaf(R[n * 152 + k * 8 + c], sw2[d * 8 + c], s);
        local2[(size_t)b * 9728 + i] = s;
    }
}

// ---------------------------------------------------------------------------
// attention: per (b,n): softmax(x^T @ local2^T) @ local2 -> cat upper half bf16
// ---------------------------------------------------------------------------
__global__ __launch_bounds__(256) void attn_kernel(
    const float* __restrict__ x, const float* __restrict__ local2,
    unsigned short* __restrict__ cat) {
    __shared__ float L[152];
    const int bn = blockIdx.x;  // 512
    const int b = bn >> 6, n = bn & 63;
    const int tid = threadIdx.x;
    if (tid < 152) L[tid] = local2[(size_t)bn * 152 + tid];
    __syncthreads();
    for (int i = 0; i < 16; ++i) {
        const int p = i * 256 + tid;
        float xv[8];
#pragma unroll
        for (int c = 0; c < 8; ++c)
            xv[c] = x[((size_t)(b * 512 + n * 8 + c)) * 4096 + p];
        float lg[19];
        float mx = -1e30f;
#pragma unroll
        for (int k = 0; k < 19; ++k) {
            float s = 0.f;
#pragma unroll
            for (int c = 0; c < 8; ++c) s = fmaf(xv[c], L[k * 8 + c], s);
            lg[k] = s;
            mx = fmaxf(mx, s);
        }
        float se = 0.f;
#pragma unroll
        for (int k = 0; k < 19; ++k) {
            lg[k] = __expf(lg[k] - mx);
            se += lg[k];
        }
        const float inv = 1.f / se;
        float ov[8];
#pragma unroll
        for (int c = 0; c < 8; ++c) ov[c] = 0.f;
#pragma unroll
        for (int k = 0; k < 19; ++k) {
#pragma unroll
            for (int c = 0; c < 8; ++c) ov[c] = fmaf(lg[k], L[k * 8 + c], ov[c]);
        }
        u16x8 w;
#pragma unroll
        for (int c = 0; c < 8; ++c) w[c] = f2bf(ov[c] * inv);
        *(u16x8*)(cat + ((size_t)(b * 4096) + p) * 1024 + 512 + n * 8) = w;
    }
}

// ---------------------------------------------------------------------------
// conv 3x3 SAME implicit GEMM, m97 structure: 128px x 128oc tile, BK=64,
// global_load_lds(16B) staging, XOR-swizzled LDS (pre-swizzled global src,
// linear LDS dest, swizzled ds_read).  OOB pixels read from a zero page.
// ---------------------------------------------------------------------------
__global__ __launch_bounds__(256) void conv_kernel(
    const unsigned short* __restrict__ cat, const unsigned short* __restrict__ wt,
    const unsigned short* __restrict__ zp,
    const float* __restrict__ gamma, const float* __restrict__ beta,
    float* __restrict__ out) {
    __shared__ __align__(16) unsigned short As[128 * 64];
    __shared__ __align__(16) unsigned short Bs[128 * 64];
    const int bid0 = blockIdx.x;                       // 1024 blocks
    const int bid = (bid0 & 7) * 128 + (bid0 >> 3);    // XCD-bijective swizzle
    const int pt = bid >> 2;     // pixel tile 0..255 (128 px = 2 image rows)
    const int ot = bid & 3;      // oc tile 0..3
    const int b = pt >> 5;
    const int y0 = (pt & 31) * 2;
    const int oc0 = ot * 128;
    const int tid = threadIdx.x;
    const int lane = tid & 63;
    const int wave = tid >> 6;
    const int wr = (wave >> 1) * 64;  // wave pixel offset
    const int wc = (wave & 1) * 64;   // wave oc offset
    const int l16 = lane & 15;
    const int khalf = lane >> 4;      // 0..3

    // staging geometry: LDS linear offset o = q*4096 + tid*16 bytes
    // row = o>>7 (stride 64 shorts = 128B), swizzle: colbyte = (o&127)^((row&7)<<4)
    const int subrow = tid >> 3;                         // 0..31
    const int icoff = ((tid & 7) ^ (subrow & 7)) << 3;   // element offset 0..56

    int prow_[4], pcol_[4];
    size_t boff_[4];
#pragma unroll
    for (int q = 0; q < 4; ++q) {
        const int row = q * 32 + subrow;
        prow_[q] = row >> 6;
        pcol_[q] = row & 63;
        boff_[q] = (size_t)(oc0 + row) * 1024 + icoff;
    }

    // fragment ds_read offsets (shorts): logical colbyte = ks*64 + khalf*16,
    // physical = logical ^ ((r&7)<<4), r&7 == l16&7 for all frags
    int colks[2];
#pragma unroll
    for (int ks = 0; ks < 2; ++ks)
        colks[ks] = ((ks * 64 + khalf * 16) ^ ((l16 & 7) << 4)) >> 1;

    f32x4 acc[4][4];
#pragma unroll
    for (int m = 0; m < 4; ++m)
#pragma unroll
        for (int n = 0; n < 4; ++n)
#pragma unroll
            for (int j = 0; j < 4; ++j) acc[m][n][j] = 0.f;

    for (int tap = 0; tap < 9; ++tap) {
        const int dy = tap / 3 - 1;
        const int dx = tap % 3 - 1;
        const unsigned short* baseA[4];
#pragma unroll
        for (int q = 0; q < 4; ++q) {
            const int yy = y0 + prow_[q] + dy;
            const int xx = pcol_[q] + dx;
            const bool ok = ((unsigned)yy < 64u) && ((unsigned)xx < 64u);
            baseA[q] = ok ? cat + (size_t)(b * 4096 + yy * 64 + xx) * 1024 + icoff
                          : zp + icoff;
        }
        const unsigned short* baseB = wt + (size_t)tap * 524288;
        for (int ics = 0; ics < 16; ++ics) {
            const int ic0 = ics << 6;
#pragma unroll
            for (int q = 0; q < 4; ++q)
                gload16(As + q * 2048 + tid * 8, baseA[q] + ic0);
#pragma unroll
            for (int q = 0; q < 4; ++q)
                gload16(Bs + q * 2048 + tid * 8, baseB + boff_[q] + ic0);
            __syncthreads();
#pragma unroll
            for (int ks = 0; ks < 2; ++ks) {
                bf16x8 af[4], bg[4];
#pragma unroll
                for (int m = 0; m < 4; ++m)
                    af[m] = *(const bf16x8*)(As + (wr + m * 16 + l16) * 64 + colks[ks]);
#pragma unroll
                for (int n = 0; n < 4; ++n)
                    bg[n] = *(const bf16x8*)(Bs + (wc + n * 16 + l16) * 64 + colks[ks]);
#pragma unroll
                for (int m = 0; m < 4; ++m)
#pragma unroll
                    for (int n = 0; n < 4; ++n)
                        acc[m][n] = __builtin_amdgcn_mfma_f32_16x16x32_bf16(
                            af[m], bg[n], acc[m][n], 0, 0, 0);
            }
            __syncthreads();
        }
    }
    // epilogue: affine + relu, f32 out.  C/D: col(oc)=lane&15, row=(lane>>4)*4+j
    const int pbase = (pt & 31) * 128;
#pragma unroll
    for (int n = 0; n < 4; ++n) {
        const int oc = oc0 + wc + n * 16 + l16;
        const float g = gamma[oc], bb = beta[oc];
#pragma unroll
        for (int m = 0; m < 4; ++m) {
            const int pr = wr + m * 16 + khalf * 4;
            float4 o;
            o.x = fmaxf(fmaf(acc[m][n][0], g, bb), 0.f);
            o.y = fmaxf(fmaf(acc[m][n][1], g, bb), 0.f);
            o.z = fmaxf(fmaf(acc[m][n][2], g, bb), 0.f);
            o.w = fmaxf(fmaf(acc[m][n][3], g, bb), 0.f);
            *(float4*)(out + ((size_t)(b * 512 + oc)) * 4096 + pbase + pr) = o;
        }
    }
}

// ---------------------------------------------------------------------------
extern "C" void kernel_launch(void* const* d_in, const int* in_sizes, int n_in,
                              void* d_out, int out_size, void* d_ws, size_t ws_size,
                              hipStream_t stream) {
    const float* x = (const float*)d_in[0];
    const float* dct = (const float*)d_in[1];
    const float* dm_w1 = (const float*)d_in[2];
    const float* dm_g = (const float*)d_in[3];
    const float* dm_b = (const float*)d_in[4];
    const float* dm_w2 = (const float*)d_in[5];
    const float* dm_b2 = (const float*)d_in[6];
    const float* fuse_w = (const float*)d_in[7];
    const float* fuse_b = (const float*)d_in[8];
    const float* gcn_w1 = (const float*)d_in[9];
    const float* gcn_w2 = (const float*)d_in[10];
    const float* bot_w = (const float*)d_in[11];
    const float* bot_g = (const float*)d_in[12];
    const float* bot_b = (const float*)d_in[13];

    float* y = (float*)d_out;
    float* out1 = y + (size_t)8 * 512 * 4096;

    char* ws = (char*)d_ws;
    const size_t CAT_BYTES = (size_t)8 * 4096 * 1024 * 2;     // 67108864
    const size_t WT_BYTES = (size_t)9 * 512 * 1024 * 2;       // 9437184
    const size_t PART_BYTES = (size_t)2048 * 152 * 4;         // 1245184
    const size_t L2_BYTES = (size_t)8 * 9728 * 4;             // 311296
    const size_t ZP_BYTES = 4096;
    if (ws_size < CAT_BYTES + WT_BYTES + PART_BYTES + L2_BYTES + ZP_BYTES) return;

    unsigned short* cat = (unsigned short*)ws;
    unsigned short* wt = (unsigned short*)(ws + CAT_BYTES);
    float* part = (float*)(ws + CAT_BYTES + WT_BYTES);
    float* local2 = (float*)(ws + CAT_BYTES + WT_BYTES + PART_BYTES);
    unsigned short* zp = (unsigned short*)(ws + CAT_BYTES + WT_BYTES + PART_BYTES + L2_BYTES);
    // fuse partials transiently reuse the cat region (consumed before x_to_cat)
    float* fpart = (float*)ws;

    hipMemsetAsync(zp, 0, ZP_BYTES, stream);
    local_kernel<<<dim3(2048), dim3(256), 0, stream>>>(x, dct, dm_w1, dm_g, dm_b,
                                                       dm_w2, dm_b2, part);
    fuse_part<<<dim3(1024), dim3(256), 0, stream>>>(x, dct, dm_w1, dm_g, dm_b,
                                                    dm_w2, dm_b2, fuse_w, fpart);
    fuse_reduce<<<dim3(2432), dim3(256), 0, stream>>>(fpart, fuse_b, out1);
    gcn_kernel<<<dim3(8), dim3(256), 0, stream>>>(part, gcn_w1, gcn_w2, local2);
    repack_w<<<dim3(18432), dim3(256), 0, stream>>>(bot_w, wt);
    x_to_cat<<<dim3(4096), dim3(256), 0, stream>>>(x, cat);
    attn_kernel<<<dim3(512), dim3(256), 0, stream>>>(x, local2, cat);
    conv_kernel<<<dim3(1024), dim3(256), 0, stream>>>(cat, wt, zp, bot_g, bot_b, y);
}

// Round 4
// 553.631 us; speedup vs baseline: 1.6616x; 1.1157x over previous
//
#include <hip/hip_runtime.h>

// Problem constants
// B=8, C=512, H=W=64, HW=4096, NUM=64, CG=8, NC=19, OUT=512, ICAT=1024

typedef __attribute__((ext_vector_type(8))) unsigned short u16x8;
typedef __attribute__((ext_vector_type(8))) __bf16 bf16x8;
typedef __attribute__((ext_vector_type(4))) float f32x4;

__device__ inline unsigned short f2bf(float f) {
    unsigned int u = __float_as_uint(f);
    u += 0x7fffu + ((u >> 16) & 1u);
    return (unsigned short)(u >> 16);
}

__device__ __forceinline__ void gload16(unsigned short* lds, const unsigned short* g) {
    __builtin_amdgcn_global_load_lds(
        (const __attribute__((address_space(1))) unsigned int*)g,
        (__attribute__((address_space(3))) unsigned int*)lds, 16, 0, 0);
}

// ---------------------------------------------------------------------------
// Repack bot_w [512][1024][3][3] f32 -> wt[tap][oc][ic] bf16
// ---------------------------------------------------------------------------
__global__ __launch_bounds__(256) void repack_w(const float* __restrict__ w,
                                                unsigned short* __restrict__ wt) {
    int i = blockIdx.x * 256 + threadIdx.x;  // 9*512*1024 = 4718592
    if (i >= 9 * 512 * 1024) return;
    int ic = i & 1023;
    int oc = (i >> 10) & 511;
    int tap = i >> 19;
    float v = w[((size_t)oc * 1024 + ic) * 9 + tap];
    wt[i] = f2bf(v);
}

// ---------------------------------------------------------------------------
// local partials: per (b,n,split) block computes partial local[19][8] over
// 1024 pixels (4 chunks of 256).  part[(bn*4+sp)*152 + k*8+c]
// ---------------------------------------------------------------------------
__global__ __launch_bounds__(256) void local_kernel(
    const float* __restrict__ x, const float* __restrict__ dct,
    const float* __restrict__ w1, const float* __restrict__ gamma,
    const float* __restrict__ beta, const float* __restrict__ w2,
    const float* __restrict__ b2, float* __restrict__ part) {
    __shared__ __align__(16) float fgs[8][260];
    __shared__ __align__(16) float fms[19][260];
    __shared__ float sw1[64], sw2[152], sb2[19], sg[8], sb[8];
    const int bid = blockIdx.x;  // 2048
    const int bn = bid >> 2;
    const int sp = bid & 3;
    const int b = bn >> 6, n = bn & 63;
    const int tid = threadIdx.x;
    if (tid < 64) sw1[tid] = w1[tid];
    if (tid < 152) sw2[tid] = w2[tid];
    if (tid < 19) sb2[tid] = b2[tid];
    if (tid < 8) { sg[tid] = gamma[tid]; sb[tid] = beta[tid]; }
    __syncthreads();
    float accv = 0.f;
    const int kk = tid >> 3, cc = tid & 7;
    for (int ch = 0; ch < 4; ++ch) {
        const int p = (sp * 4 + ch) * 256 + tid;
        float fg[8];
#pragma unroll
        for (int c = 0; c < 8; ++c) {
            fg[c] = x[((size_t)(b * 512 + n * 8 + c)) * 4096 + p] *
                    dct[((size_t)(n * 8 + c)) * 4096 + p];
            fgs[c][tid] = fg[c];
        }
        float h1[8];
#pragma unroll
        for (int d = 0; d < 8; ++d) {
            float s = 0.f;
#pragma unroll
            for (int c = 0; c < 8; ++c) s = fmaf(sw1[d * 8 + c], fg[c], s);
            h1[d] = fmaxf(fmaf(s, sg[d], sb[d]), 0.f);
        }
#pragma unroll
        for (int k = 0; k < 19; ++k) {
            float s = sb2[k];
#pragma unroll
            for (int d = 0; d < 8; ++d) s = fmaf(sw2[k * 8 + d], h1[d], s);
            fms[k][tid] = s;
        }
        __syncthreads();
        if (tid < 152) {
#pragma unroll 8
            for (int p4 = 0; p4 < 256; p4 += 4) {
                const float4 a = *(const float4*)&fms[kk][p4];
                const float4 g4 = *(const float4*)&fgs[cc][p4];
                accv += a.x * g4.x + a.y * g4.y + a.z * g4.z + a.w * g4.w;
            }
        }
        __syncthreads();
    }
    if (tid < 152) part[(size_t)bid * 152 + tid] = accv;
}

// ---------------------------------------------------------------------------
// fuse partial: split over 8 group-chunks for occupancy.
// ---------------------------------------------------------------------------
__global__ __launch_bounds__(256) void fuse_part(
    const float* __restrict__ x, const float* __restrict__ dct,
    const float* __restrict__ w1, const float* __restrict__ gamma,
    const float* __restrict__ beta, const float* __restrict__ w2,
    const float* __restrict__ b2, const float* __restrict__ fuse_w,
    float* __restrict__ fpart) {
    __shared__ float sw1[64], sw2[152], sb2[19], sg[8], sb[8], sfw[64];
    const int tid = threadIdx.x;
    if (tid < 64) { sw1[tid] = w1[tid]; sfw[tid] = fuse_w[tid]; }
    if (tid < 152) sw2[tid] = w2[tid];
    if (tid < 19) sb2[tid] = b2[tid];
    if (tid < 8) { sg[tid] = gamma[tid]; sb[tid] = beta[tid]; }
    __syncthreads();
    const int bid = blockIdx.x;  // 1024
    const int sp = bid >> 7;
    const int rest = bid & 127;
    const int b = rest >> 4;
    const int p = (rest & 15) * 256 + tid;
    float facc[19];
#pragma unroll
    for (int k = 0; k < 19; ++k) facc[k] = 0.f;
    for (int nn = 0; nn < 8; ++nn) {
        const int n = sp * 8 + nn;
        float fg[8];
#pragma unroll
        for (int c = 0; c < 8; ++c)
            fg[c] = x[((size_t)(b * 512 + n * 8 + c)) * 4096 + p] *
                    dct[((size_t)(n * 8 + c)) * 4096 + p];
        float h1[8];
#pragma unroll
        for (int d = 0; d < 8; ++d) {
            float s = 0.f;
#pragma unroll
            for (int c = 0; c < 8; ++c) s = fmaf(sw1[d * 8 + c], fg[c], s);
            h1[d] = fmaxf(fmaf(s, sg[d], sb[d]), 0.f);
        }
        const float fw = sfw[n];
#pragma unroll
        for (int k = 0; k < 19; ++k) {
            float s = sb2[k];
#pragma unroll
            for (int d = 0; d < 8; ++d) s = fmaf(sw2[k * 8 + d], h1[d], s);
            facc[k] = fmaf(fw, s, facc[k]);
        }
    }
#pragma unroll
    for (int k = 0; k < 19; ++k)
        fpart[((size_t)(sp * 8 + b) * 19 + k) * 4096 + p] = facc[k];
}

__global__ __launch_bounds__(256) void fuse_reduce(
    const float* __restrict__ fpart, const float* __restrict__ fuse_b,
    float* __restrict__ out1) {
    const int i = blockIdx.x * 256 + threadIdx.x;  // 622592 total
    float s = fuse_b[0];
#pragma unroll
    for (int sp = 0; sp < 8; ++sp) s += fpart[(size_t)sp * 622592 + i];
    out1[i] = s;
}

// ---------------------------------------------------------------------------
// GCN
// ---------------------------------------------------------------------------
__global__ __launch_bounds__(256) void gcn_kernel(
    const float* __restrict__ part, const float* __restrict__ w1,
    const float* __restrict__ w2, float* __restrict__ local2) {
    __shared__ float L[9728];
    __shared__ float R[9728];
    __shared__ float sw1[4096];
    __shared__ float sw2[64];
    const int b = blockIdx.x;
    const int tid = threadIdx.x;
    for (int i = tid; i < 4096; i += 256) sw1[i] = w1[i];
    if (tid < 64) sw2[tid] = w2[tid];
    for (int i = tid; i < 9728; i += 256) {
        int n = i / 152, t = i - n * 152;
        float s = 0.f;
#pragma unroll
        for (int sp = 0; sp < 4; ++sp)
            s += part[((size_t)((b * 64 + n) * 4 + sp)) * 152 + t];
        L[i] = s;
    }
    __syncthreads();
    for (int i = tid; i < 9728; i += 256) {
        int m = i / 152, t = i - m * 152;
        float g = 0.f;
        for (int n = 0; n < 64; ++n) g = fmaf(sw1[m * 64 + n], L[n * 152 + t], g);
        R[i] = fmaxf(g + L[i], 0.f);
    }
    __syncthreads();
    for (int i = tid; i < 9728; i += 256) {
        int n = i / 152, t = i - n * 152;
        int k = t >> 3, d = t & 7;
        float s = 0.f;
#pragma unroll
        for (int c = 0; c < 8; ++c) s = fmaf(R[n * 152 + k * 8 + c], sw2[d * 8 + c], s);
        local2[(size_t)b * 9728 + i] = s;
    }
}

// ---------------------------------------------------------------------------
// attention + x copy: per (b,n) writes BOTH cat halves (x bf16 lower,
// softmax(x@L^T)@L upper)
// ---------------------------------------------------------------------------
__global__ __launch_bounds__(256) void attn_kernel(
    const float* __restrict__ x, const float* __restrict__ local2,
    unsigned short* __restrict__ cat) {
    __shared__ float L[152];
    const int bn = blockIdx.x;  // 512
    const int b = bn >> 6, n = bn & 63;
    const int tid = threadIdx.x;
    if (tid < 152) L[tid] = local2[(size_t)bn * 152 + tid];
    __syncthreads();
    for (int i = 0; i < 16; ++i) {
        const int p = i * 256 + tid;
        float xv[8];
        u16x8 xw;
#pragma unroll
        for (int c = 0; c < 8; ++c) {
            xv[c] = x[((size_t)(b * 512 + n * 8 + c)) * 4096 + p];
            xw[c] = f2bf(xv[c]);
        }
        *(u16x8*)(cat + ((size_t)(b * 4096) + p) * 1024 + n * 8) = xw;
        float lg[19];
        float mx = -1e30f;
#pragma unroll
        for (int k = 0; k < 19; ++k) {
            float s = 0.f;
#pragma unroll
            for (int c = 0; c < 8; ++c) s = fmaf(xv[c], L[k * 8 + c], s);
            lg[k] = s;
            mx = fmaxf(mx, s);
        }
        float se = 0.f;
#pragma unroll
        for (int k = 0; k < 19; ++k) {
            lg[k] = __expf(lg[k] - mx);
            se += lg[k];
        }
        const float inv = 1.f / se;
        float ov[8];
#pragma unroll
        for (int c = 0; c < 8; ++c) ov[c] = 0.f;
#pragma unroll
        for (int k = 0; k < 19; ++k) {
#pragma unroll
            for (int c = 0; c < 8; ++c) ov[c] = fmaf(lg[k], L[k * 8 + c], ov[c]);
        }
        u16x8 w;
#pragma unroll
        for (int c = 0; c < 8; ++c) w[c] = f2bf(ov[c] * inv);
        *(u16x8*)(cat + ((size_t)(b * 4096) + p) * 1024 + 512 + n * 8) = w;
    }
}

// ---------------------------------------------------------------------------
// conv 3x3 SAME implicit GEMM, 256x256 8-phase template (T1+T2+T3+T4+T5).
// BM=256 px, BN=256 oc, BK=64, 512 threads (8 waves).  144 K-tiles.
// LDS: A,B x 2 parity slots x 256x64 bf16 = 128 KiB.  1 half-tile (2x
// global_load_lds 16B) staged per phase; counted vmcnt per derived ledger:
// steady-state in-flight 4..8, waits 4/4/6/4, never 0 in the loop.
// __launch_bounds__(512,1): 256-VGPR cap -> no scratch spills (spills are
// VMEM ops and would corrupt the vmcnt ledger -- round-3 failure mode).
// ---------------------------------------------------------------------------
__global__ __launch_bounds__(512, 1) void conv_kernel(
    const unsigned short* __restrict__ cat, const unsigned short* __restrict__ wt,
    const unsigned short* __restrict__ zp,
    const float* __restrict__ gamma, const float* __restrict__ beta,
    float* __restrict__ out) {
    __shared__ __align__(16) unsigned short As[2 * 16384];
    __shared__ __align__(16) unsigned short Bs[2 * 16384];
    const int bid0 = blockIdx.x;                    // 256 blocks
    const int bid = (bid0 & 7) * 32 + (bid0 >> 3);  // XCD swizzle (bijective)
    const int mt = bid >> 1;                        // 128 M-tiles
    const int nt = bid & 1;                         // 2 N-tiles
    const int b = mt >> 4;
    const int pix0 = (mt & 15) * 256;
    const int y0 = (mt & 15) * 4;
    const int ocb = nt * 256;
    const int tid = threadIdx.x;
    const int w = tid >> 6;
    const int lane = tid & 63;
    const int l16 = lane & 15;
    const int khalf = lane >> 4;
    const int wrow = (w >> 2) * 64;
    const int wcol = (w & 3) * 32;
    // staging thread-constants
    const int sx = tid >> 3;                              // 0..63 (pixel col / oc sub)
    const int icsw = ((tid & 7) ^ ((tid >> 3) & 7)) * 8;  // pre-swizzled ic offset
    const unsigned short* zps = zp + icsw;
    const unsigned short* catb = cat + ((size_t)b * 4096) * 1024 + icsw;
    // fragment ds_read swizzled column offsets (shorts)
    int colks[2];
#pragma unroll
    for (int ks = 0; ks < 2; ++ks)
        colks[ks] = ((ks * 64 + khalf * 16) ^ ((l16 & 7) << 4)) >> 1;

    f32x4 acc[2][2][4][2];
#pragma unroll
    for (int qm = 0; qm < 2; ++qm)
#pragma unroll
        for (int qn = 0; qn < 2; ++qn)
#pragma unroll
            for (int m = 0; m < 4; ++m)
#pragma unroll
                for (int n = 0; n < 2; ++n)
#pragma unroll
                    for (int j = 0; j < 4; ++j) acc[qm][qn][m][n][j] = 0.f;

    bf16x8 af[4][2];
    bf16x8 bq[2][2];

#define STAGE_A(SP, SH, DY, XOK, AB)                                               \
    _Pragma("unroll") for (int j_ = 0; j_ < 2; ++j_) {                             \
        const int yy_ = y0 + (SH) * 2 + j_ + (DY);                                 \
        const unsigned short* src_ =                                               \
            ((XOK) && ((unsigned)yy_ < 64u)) ? (AB) + yy_ * 65536 : zps;           \
        gload16(As + (SP) * 16384 + (SH) * 8192 + (j_ * 512 + tid) * 8, src_);     \
    }

#define STAGE_B(SP, SH, WB)                                                        \
    _Pragma("unroll") for (int j_ = 0; j_ < 2; ++j_) {                             \
        gload16(Bs + (SP) * 16384 + (SH) * 8192 + (j_ * 512 + tid) * 8,            \
                (WB) + (SH) * 131072 + j_ * 65536);                                \
    }

#define READ_AF(PE, QM)                                                            \
    _Pragma("unroll") for (int m_ = 0; m_ < 4; ++m_)                               \
        _Pragma("unroll") for (int ks_ = 0; ks_ < 2; ++ks_)                        \
            af[m_][ks_] = *(const bf16x8*)(As + (PE) * 16384 +                     \
                ((QM) * 128 + wrow + m_ * 16 + l16) * 64 + colks[ks_]);

#define READ_BF(PE, QN)                                                            \
    _Pragma("unroll") for (int n_ = 0; n_ < 2; ++n_)                               \
        _Pragma("unroll") for (int ks_ = 0; ks_ < 2; ++ks_)                        \
            bq[n_][ks_] = *(const bf16x8*)(Bs + (PE) * 16384 +                     \
                ((QN) * 128 + wcol + n_ * 16 + l16) * 64 + colks[ks_]);

#define SYNC_PHASE(VN)                                                             \
    asm volatile("s_waitcnt vmcnt(" #VN ")" ::: "memory");                         \
    __builtin_amdgcn_s_barrier();                                                  \
    __builtin_amdgcn_sched_barrier(0);

#define MFMA_Q(QM, QN)                                                             \
    __builtin_amdgcn_s_setprio(1);                                                 \
    _Pragma("unroll") for (int m_ = 0; m_ < 4; ++m_)                               \
        _Pragma("unroll") for (int n_ = 0; n_ < 2; ++n_)                           \
            _Pragma("unroll") for (int ks_ = 0; ks_ < 2; ++ks_)                    \
                acc[QM][QN][m_][n_] = __builtin_amdgcn_mfma_f32_16x16x32_bf16(     \
                    af[m_][ks_], bq[n_][ks_], acc[QM][QN][m_][n_], 0, 0, 0);       \
    __builtin_amdgcn_s_setprio(0);

    // prologue: K-tile 0 (tap 0: dy=-1,dx=-1, ic=0) into parity-0 slots
    {
        const bool xok_p = sx >= 1;
        const unsigned short* ab_p = catb + (sx - 1) * 1024;
        const unsigned short* wb_p = wt + (size_t)(ocb + sx) * 1024 + icsw;
        STAGE_A(0, 0, -1, xok_p, ab_p);
        STAGE_B(0, 0, wb_p);
        STAGE_B(0, 1, wb_p);
        STAGE_A(0, 1, -1, xok_p, ab_p);
    }
    SYNC_PHASE(4)

    for (int i = 0; i < 72; ++i) {
        const int kto = 2 * i + 1;
        const int ktn = (i == 71) ? 0 : 2 * i + 2;  // dummy wrap keeps ledger invariant
        // per-K-tile staging params (hoisted out of phases)
        const int tap_o = kto >> 4;
        const int dy_o = tap_o / 3 - 1;
        const int dx_o = tap_o % 3 - 1;
        const int ic_o = (kto & 15) << 6;
        const bool xok_o = (unsigned)(sx + dx_o) < 64u;
        const unsigned short* ab_o = catb + (sx + dx_o) * 1024 + ic_o;
        const unsigned short* wb_o = wt + ((size_t)tap_o << 19) +
                                     (size_t)(ocb + sx) * 1024 + ic_o + icsw;
        const int tap_n = ktn >> 4;
        const int dy_n = tap_n / 3 - 1;
        const int dx_n = tap_n % 3 - 1;
        const int ic_n = (ktn & 15) << 6;
        const bool xok_n = (unsigned)(sx + dx_n) < 64u;
        const unsigned short* ab_n = catb + (sx + dx_n) * 1024 + ic_n;
        const unsigned short* wb_n = wt + ((size_t)tap_n << 19) +
                                     (size_t)(ocb + sx) * 1024 + ic_n + icsw;
        // ph1: q(0,0) on even parity; stage O.Ah0
        READ_AF(0, 0) READ_BF(0, 0)
        STAGE_A(1, 0, dy_o, xok_o, ab_o);
        SYNC_PHASE(4)
        MFMA_Q(0, 0)
        // ph2: q(0,1); stage O.Bh0
        READ_BF(0, 1)
        STAGE_B(1, 0, wb_o);
        SYNC_PHASE(4)
        MFMA_Q(0, 1)
        // ph3: q(1,0); stage O.Bh1
        READ_AF(0, 1) READ_BF(0, 0)
        STAGE_B(1, 1, wb_o);
        SYNC_PHASE(6)
        MFMA_Q(1, 0)
        // ph4: q(1,1); stage O.Ah1
        READ_BF(0, 1)
        STAGE_A(1, 1, dy_o, xok_o, ab_o);
        SYNC_PHASE(4)
        MFMA_Q(1, 1)
        // ph5: q(0,0) on odd parity; stage E'.Ah0
        READ_AF(1, 0) READ_BF(1, 0)
        STAGE_A(0, 0, dy_n, xok_n, ab_n);
        SYNC_PHASE(4)
        MFMA_Q(0, 0)
        // ph6: q(0,1); stage E'.Bh0
        READ_BF(1, 1)
        STAGE_B(0, 0, wb_n);
        SYNC_PHASE(4)
        MFMA_Q(0, 1)
        // ph7: q(1,0); stage E'.Bh1
        READ_AF(1, 1) READ_BF(1, 0)
        STAGE_B(0, 1, wb_n);
        SYNC_PHASE(6)
        MFMA_Q(1, 0)
        // ph8: q(1,1); stage E'.Ah1
        READ_BF(1, 1)
        STAGE_A(0, 1, dy_n, xok_n, ab_n);
        SYNC_PHASE(4)
        MFMA_Q(1, 1)
    }
    asm volatile("s_waitcnt vmcnt(0)" ::: "memory");

    // epilogue: affine + relu, f32 out.  C/D: col(oc)=l16, row=khalf*4+j
#pragma unroll
    for (int qn = 0; qn < 2; ++qn)
#pragma unroll
        for (int n = 0; n < 2; ++n) {
            const int oc = ocb + qn * 128 + wcol + n * 16 + l16;
            const float g = gamma[oc], bb = beta[oc];
#pragma unroll
            for (int qm = 0; qm < 2; ++qm)
#pragma unroll
                for (int m = 0; m < 4; ++m) {
                    const int P = qm * 128 + wrow + m * 16 + khalf * 4;
                    float4 o;
                    o.x = fmaxf(fmaf(acc[qm][qn][m][n][0], g, bb), 0.f);
                    o.y = fmaxf(fmaf(acc[qm][qn][m][n][1], g, bb), 0.f);
                    o.z = fmaxf(fmaf(acc[qm][qn][m][n][2], g, bb), 0.f);
                    o.w = fmaxf(fmaf(acc[qm][qn][m][n][3], g, bb), 0.f);
                    *(float4*)(out + ((size_t)(b * 512 + oc)) * 4096 + pix0 + P) = o;
                }
        }
#undef STAGE_A
#undef STAGE_B
#undef READ_AF
#undef READ_BF
#undef SYNC_PHASE
#undef MFMA_Q
}

// ---------------------------------------------------------------------------
extern "C" void kernel_launch(void* const* d_in, const int* in_sizes, int n_in,
                              void* d_out, int out_size, void* d_ws, size_t ws_size,
                              hipStream_t stream) {
    const float* x = (const float*)d_in[0];
    const float* dct = (const float*)d_in[1];
    const float* dm_w1 = (const float*)d_in[2];
    const float* dm_g = (const float*)d_in[3];
    const float* dm_b = (const float*)d_in[4];
    const float* dm_w2 = (const float*)d_in[5];
    const float* dm_b2 = (const float*)d_in[6];
    const float* fuse_w = (const float*)d_in[7];
    const float* fuse_b = (const float*)d_in[8];
    const float* gcn_w1 = (const float*)d_in[9];
    const float* gcn_w2 = (const float*)d_in[10];
    const float* bot_w = (const float*)d_in[11];
    const float* bot_g = (const float*)d_in[12];
    const float* bot_b = (const float*)d_in[13];

    float* y = (float*)d_out;
    float* out1 = y + (size_t)8 * 512 * 4096;

    char* ws = (char*)d_ws;
    const size_t CAT_BYTES = (size_t)8 * 4096 * 1024 * 2;     // 67108864
    const size_t WT_BYTES = (size_t)9 * 512 * 1024 * 2;       // 9437184
    const size_t PART_BYTES = (size_t)2048 * 152 * 4;         // 1245184
    const size_t L2_BYTES = (size_t)8 * 9728 * 4;             // 311296
    const size_t ZP_BYTES = 4096;
    if (ws_size < CAT_BYTES + WT_BYTES + PART_BYTES + L2_BYTES + ZP_BYTES) return;

    unsigned short* cat = (unsigned short*)ws;
    unsigned short* wt = (unsigned short*)(ws + CAT_BYTES);
    float* part = (float*)(ws + CAT_BYTES + WT_BYTES);
    float* local2 = (float*)(ws + CAT_BYTES + WT_BYTES + PART_BYTES);
    unsigned short* zp = (unsigned short*)(ws + CAT_BYTES + WT_BYTES + PART_BYTES + L2_BYTES);
    // fuse partials transiently reuse the cat region (consumed before attn)
    float* fpart = (float*)ws;

    hipMemsetAsync(zp, 0, ZP_BYTES, stream);
    local_kernel<<<dim3(2048), dim3(256), 0, stream>>>(x, dct, dm_w1, dm_g, dm_b,
                                                       dm_w2, dm_b2, part);
    fuse_part<<<dim3(1024), dim3(256), 0, stream>>>(x, dct, dm_w1, dm_g, dm_b,
                                                    dm_w2, dm_b2, fuse_w, fpart);
    fuse_reduce<<<dim3(2432), dim3(256), 0, stream>>>(fpart, fuse_b, out1);
    gcn_kernel<<<dim3(8), dim3(256), 0, stream>>>(part, gcn_w1, gcn_w2, local2);
    repack_w<<<dim3(18432), dim3(256), 0, stream>>>(bot_w, wt);
    attn_kernel<<<dim3(512), dim3(256), 0, stream>>>(x, local2, cat);
    conv_kernel<<<dim3(256), dim3(512), 0, stream>>>(cat, wt, zp, bot_g, bot_b, y);
}

// Round 5
// 454.010 us; speedup vs baseline: 2.0262x; 1.2194x over previous
//
#include <hip/hip_runtime.h>

// Problem constants
// B=8, C=512, H=W=64, HW=4096, NUM=64, CG=8, NC=19, OUT=512, ICAT=1024

typedef __attribute__((ext_vector_type(8))) unsigned short u16x8;
typedef __attribute__((ext_vector_type(8))) __bf16 bf16x8;
typedef __attribute__((ext_vector_type(4))) float f32x4;

__device__ inline unsigned short f2bf(float f) {
    unsigned int u = __float_as_uint(f);
    u += 0x7fffu + ((u >> 16) & 1u);
    return (unsigned short)(u >> 16);
}

__device__ __forceinline__ void gload16(unsigned short* lds, const unsigned short* g) {
    __builtin_amdgcn_global_load_lds(
        (const __attribute__((address_space(1))) unsigned int*)g,
        (__attribute__((address_space(3))) unsigned int*)lds, 16, 0, 0);
}

// ---------------------------------------------------------------------------
// Repack bot_w [512][1024][3][3] f32 -> wt[tap][oc][ic] bf16.
// One oc per block: coalesced reads, LDS transpose (stride-9 reads are
// bank-conflict-free: gcd(9,32)=1), contiguous bf16 writes.
// ---------------------------------------------------------------------------
__global__ __launch_bounds__(256) void repack_w(const float* __restrict__ w,
                                                unsigned short* __restrict__ wt) {
    __shared__ float buf[9216];
    const int oc = blockIdx.x;  // 512
    const int tid = threadIdx.x;
    const float* src = w + (size_t)oc * 9216;
    for (int i = tid; i < 9216; i += 256) buf[i] = src[i];
    __syncthreads();
#pragma unroll
    for (int t = 0; t < 9; ++t) {
        for (int i = tid; i < 1024; i += 256)
            wt[((size_t)t * 512 + oc) * 1024 + i] = f2bf(buf[i * 9 + t]);
    }
}

// ---------------------------------------------------------------------------
// front: fused decoder_map + fuse-partial + local-partial + x->bf16 cat.
// Grid 512 = (sp 0..3)(b 0..7)(ch 0..15); block = 256 px, 16 groups.
// Reads x,dct exactly once.  part[b][n][ch][152] and fpart[sp][b][19][4096]
// land in the d_out y region (consumed before conv overwrites y).
// ---------------------------------------------------------------------------
__global__ __launch_bounds__(256) void front_kernel(
    const float* __restrict__ x, const float* __restrict__ dct,
    const float* __restrict__ w1, const float* __restrict__ gamma,
    const float* __restrict__ beta, const float* __restrict__ w2,
    const float* __restrict__ b2, const float* __restrict__ fuse_w,
    float* __restrict__ part, float* __restrict__ fpart,
    unsigned short* __restrict__ cat) {
    __shared__ __align__(16) float fgs[8][260];
    __shared__ __align__(16) float fms[19][260];
    __shared__ float sw1[64], sw2[152], sb2[19], sg[8], sb[8], sfw[64];
    const int bid = blockIdx.x;
    const int sp = bid >> 7;
    const int b = (bid >> 4) & 7;
    const int ch = bid & 15;
    const int tid = threadIdx.x;
    if (tid < 64) { sw1[tid] = w1[tid]; sfw[tid] = fuse_w[tid]; }
    if (tid < 152) sw2[tid] = w2[tid];
    if (tid < 19) sb2[tid] = b2[tid];
    if (tid < 8) { sg[tid] = gamma[tid]; sb[tid] = beta[tid]; }
    __syncthreads();
    const int p = ch * 256 + tid;
    const int kk = tid >> 3, cc = tid & 7;
    float facc[19];
#pragma unroll
    for (int k = 0; k < 19; ++k) facc[k] = 0.f;
    for (int nn = 0; nn < 16; ++nn) {
        const int n = sp * 16 + nn;
        float fg[8];
        u16x8 xw;
#pragma unroll
        for (int c = 0; c < 8; ++c) {
            const float xv = x[((size_t)(b * 512 + n * 8 + c)) * 4096 + p];
            fg[c] = xv * dct[((size_t)(n * 8 + c)) * 4096 + p];
            xw[c] = f2bf(xv);
            fgs[c][tid] = fg[c];
        }
        *(u16x8*)(cat + ((size_t)(b * 4096) + p) * 1024 + n * 8) = xw;
        float h1[8];
#pragma unroll
        for (int d = 0; d < 8; ++d) {
            float s = 0.f;
#pragma unroll
            for (int c = 0; c < 8; ++c) s = fmaf(sw1[d * 8 + c], fg[c], s);
            h1[d] = fmaxf(fmaf(s, sg[d], sb[d]), 0.f);
        }
        const float fw = sfw[n];
#pragma unroll
        for (int k = 0; k < 19; ++k) {
            float s = sb2[k];
#pragma unroll
            for (int d = 0; d < 8; ++d) s = fmaf(sw2[k * 8 + d], h1[d], s);
            fms[k][tid] = s;
            facc[k] = fmaf(fw, s, facc[k]);
        }
        __syncthreads();
        if (tid < 152) {
            float accv = 0.f;
#pragma unroll 8
            for (int p4 = 0; p4 < 256; p4 += 4) {
                const float4 a = *(const float4*)&fms[kk][p4];
                const float4 g4 = *(const float4*)&fgs[cc][p4];
                accv += a.x * g4.x + a.y * g4.y + a.z * g4.z + a.w * g4.w;
            }
            part[((size_t)((b * 64 + n) * 16) + ch) * 152 + tid] = accv;
        }
        __syncthreads();
    }
#pragma unroll
    for (int k = 0; k < 19; ++k)
        fpart[((size_t)(sp * 8 + b) * 19 + k) * 4096 + p] = facc[k];
}

__global__ __launch_bounds__(256) void fuse_reduce(
    const float* __restrict__ fpart, const float* __restrict__ fuse_b,
    float* __restrict__ out1) {
    const int i = blockIdx.x * 256 + threadIdx.x;  // 622592 total
    float s = fuse_b[0];
#pragma unroll
    for (int sp = 0; sp < 4; ++sp) s += fpart[(size_t)sp * 622592 + i];
    out1[i] = s;
}

// ---------------------------------------------------------------------------
// GCN: sums 16 chunk-partials -> local; g = relu(w1@local + local); g@w2^T
// ---------------------------------------------------------------------------
__global__ __launch_bounds__(256) void gcn_kernel(
    const float* __restrict__ part, const float* __restrict__ w1,
    const float* __restrict__ w2, float* __restrict__ local2) {
    __shared__ float L[9728];
    __shared__ float R[9728];
    __shared__ float sw1[4096];
    __shared__ float sw2[64];
    const int b = blockIdx.x;
    const int tid = threadIdx.x;
    for (int i = tid; i < 4096; i += 256) sw1[i] = w1[i];
    if (tid < 64) sw2[tid] = w2[tid];
    for (int i = tid; i < 9728; i += 256) {
        int n = i / 152, t = i - n * 152;
        float s = 0.f;
#pragma unroll
        for (int ch = 0; ch < 16; ++ch)
            s += part[((size_t)((b * 64 + n) * 16) + ch) * 152 + t];
        L[i] = s;
    }
    __syncthreads();
    for (int i = tid; i < 9728; i += 256) {
        int m = i / 152, t = i - m * 152;
        float g = 0.f;
        for (int n = 0; n < 64; ++n) g = fmaf(sw1[m * 64 + n], L[n * 152 + t], g);
        R[i] = fmaxf(g + L[i], 0.f);
    }
    __syncthreads();
    for (int i = tid; i < 9728; i += 256) {
        int n = i / 152, t = i - n * 152;
        int k = t >> 3, d = t & 7;
        float s = 0.f;
#pragma unroll
        for (int c = 0; c < 8; ++c) s = fmaf(R[n * 152 + k * 8 + c], sw2[d * 8 + c], s);
        local2[(size_t)b * 9728 + i] = s;
    }
}

// ---------------------------------------------------------------------------
// attention: per (b,n): softmax(x@L^T)@L -> cat upper half bf16
// ---------------------------------------------------------------------------
__global__ __launch_bounds__(256) void attn_kernel(
    const float* __restrict__ x, const float* __restrict__ local2,
    unsigned short* __restrict__ cat) {
    __shared__ float L[152];
    const int bn = blockIdx.x;  // 512
    const int b = bn >> 6, n = bn & 63;
    const int tid = threadIdx.x;
    if (tid < 152) L[tid] = local2[(size_t)bn * 152 + tid];
    __syncthreads();
    for (int i = 0; i < 16; ++i) {
        const int p = i * 256 + tid;
        float xv[8];
#pragma unroll
        for (int c = 0; c < 8; ++c)
            xv[c] = x[((size_t)(b * 512 + n * 8 + c)) * 4096 + p];
        float lg[19];
        float mx = -1e30f;
#pragma unroll
        for (int k = 0; k < 19; ++k) {
            float s = 0.f;
#pragma unroll
            for (int c = 0; c < 8; ++c) s = fmaf(xv[c], L[k * 8 + c], s);
            lg[k] = s;
            mx = fmaxf(mx, s);
        }
        float se = 0.f;
#pragma unroll
        for (int k = 0; k < 19; ++k) {
            lg[k] = __expf(lg[k] - mx);
            se += lg[k];
        }
        const float inv = 1.f / se;
        float ov[8];
#pragma unroll
        for (int c = 0; c < 8; ++c) ov[c] = 0.f;
#pragma unroll
        for (int k = 0; k < 19; ++k) {
#pragma unroll
            for (int c = 0; c < 8; ++c) ov[c] = fmaf(lg[k], L[k * 8 + c], ov[c]);
        }
        u16x8 w;
#pragma unroll
        for (int c = 0; c < 8; ++c) w[c] = f2bf(ov[c] * inv);
        *(u16x8*)(cat + ((size_t)(b * 4096) + p) * 1024 + 512 + n * 8) = w;
    }
}

// ---------------------------------------------------------------------------
// conv 3x3 SAME implicit GEMM, 256x256 8-phase template (T1+T2+T3+T4+T5).
// Unchanged from round 4 (288 us, MfmaUtil 46%, 0 bank conflicts).
// ---------------------------------------------------------------------------
__global__ __launch_bounds__(512, 1) void conv_kernel(
    const unsigned short* __restrict__ cat, const unsigned short* __restrict__ wt,
    const unsigned short* __restrict__ zp,
    const float* __restrict__ gamma, const float* __restrict__ beta,
    float* __restrict__ out) {
    __shared__ __align__(16) unsigned short As[2 * 16384];
    __shared__ __align__(16) unsigned short Bs[2 * 16384];
    const int bid0 = blockIdx.x;                    // 256 blocks
    const int bid = (bid0 & 7) * 32 + (bid0 >> 3);  // XCD swizzle (bijective)
    const int mt = bid >> 1;                        // 128 M-tiles
    const int nt = bid & 1;                         // 2 N-tiles
    const int b = mt >> 4;
    const int pix0 = (mt & 15) * 256;
    const int y0 = (mt & 15) * 4;
    const int ocb = nt * 256;
    const int tid = threadIdx.x;
    const int w = tid >> 6;
    const int lane = tid & 63;
    const int l16 = lane & 15;
    const int khalf = lane >> 4;
    const int wrow = (w >> 2) * 64;
    const int wcol = (w & 3) * 32;
    const int sx = tid >> 3;                              // 0..63
    const int icsw = ((tid & 7) ^ ((tid >> 3) & 7)) * 8;  // pre-swizzled ic offset
    const unsigned short* zps = zp + icsw;
    const unsigned short* catb = cat + ((size_t)b * 4096) * 1024 + icsw;
    int colks[2];
#pragma unroll
    for (int ks = 0; ks < 2; ++ks)
        colks[ks] = ((ks * 64 + khalf * 16) ^ ((l16 & 7) << 4)) >> 1;

    f32x4 acc[2][2][4][2];
#pragma unroll
    for (int qm = 0; qm < 2; ++qm)
#pragma unroll
        for (int qn = 0; qn < 2; ++qn)
#pragma unroll
            for (int m = 0; m < 4; ++m)
#pragma unroll
                for (int n = 0; n < 2; ++n)
#pragma unroll
                    for (int j = 0; j < 4; ++j) acc[qm][qn][m][n][j] = 0.f;

    bf16x8 af[4][2];
    bf16x8 bq[2][2];

#define STAGE_A(SP, SH, DY, XOK, AB)                                               \
    _Pragma("unroll") for (int j_ = 0; j_ < 2; ++j_) {                             \
        const int yy_ = y0 + (SH) * 2 + j_ + (DY);                                 \
        const unsigned short* src_ =                                               \
            ((XOK) && ((unsigned)yy_ < 64u)) ? (AB) + yy_ * 65536 : zps;           \
        gload16(As + (SP) * 16384 + (SH) * 8192 + (j_ * 512 + tid) * 8, src_);     \
    }

#define STAGE_B(SP, SH, WB)                                                        \
    _Pragma("unroll") for (int j_ = 0; j_ < 2; ++j_) {                             \
        gload16(Bs + (SP) * 16384 + (SH) * 8192 + (j_ * 512 + tid) * 8,            \
                (WB) + (SH) * 131072 + j_ * 65536);                                \
    }

#define READ_AF(PE, QM)                                                            \
    _Pragma("unroll") for (int m_ = 0; m_ < 4; ++m_)                               \
        _Pragma("unroll") for (int ks_ = 0; ks_ < 2; ++ks_)                        \
            af[m_][ks_] = *(const bf16x8*)(As + (PE) * 16384 +                     \
                ((QM) * 128 + wrow + m_ * 16 + l16) * 64 + colks[ks_]);

#define READ_BF(PE, QN)                                                            \
    _Pragma("unroll") for (int n_ = 0; n_ < 2; ++n_)                               \
        _Pragma("unroll") for (int ks_ = 0; ks_ < 2; ++ks_)                        \
            bq[n_][ks_] = *(const bf16x8*)(Bs + (PE) * 16384 +                     \
                ((QN) * 128 + wcol + n_ * 16 + l16) * 64 + colks[ks_]);

#define SYNC_PHASE(VN)                                                             \
    asm volatile("s_waitcnt vmcnt(" #VN ")" ::: "memory");                         \
    __builtin_amdgcn_s_barrier();                                                  \
    __builtin_amdgcn_sched_barrier(0);

#define MFMA_Q(QM, QN)                                                             \
    __builtin_amdgcn_s_setprio(1);                                                 \
    _Pragma("unroll") for (int m_ = 0; m_ < 4; ++m_)                               \
        _Pragma("unroll") for (int n_ = 0; n_ < 2; ++n_)                           \
            _Pragma("unroll") for (int ks_ = 0; ks_ < 2; ++ks_)                    \
                acc[QM][QN][m_][n_] = __builtin_amdgcn_mfma_f32_16x16x32_bf16(     \
                    af[m_][ks_], bq[n_][ks_], acc[QM][QN][m_][n_], 0, 0, 0);       \
    __builtin_amdgcn_s_setprio(0);

    {
        const bool xok_p = sx >= 1;
        const unsigned short* ab_p = catb + (sx - 1) * 1024;
        const unsigned short* wb_p = wt + (size_t)(ocb + sx) * 1024 + icsw;
        STAGE_A(0, 0, -1, xok_p, ab_p);
        STAGE_B(0, 0, wb_p);
        STAGE_B(0, 1, wb_p);
        STAGE_A(0, 1, -1, xok_p, ab_p);
    }
    SYNC_PHASE(4)

    for (int i = 0; i < 72; ++i) {
        const int kto = 2 * i + 1;
        const int ktn = (i == 71) ? 0 : 2 * i + 2;
        const int tap_o = kto >> 4;
        const int dy_o = tap_o / 3 - 1;
        const int dx_o = tap_o % 3 - 1;
        const int ic_o = (kto & 15) << 6;
        const bool xok_o = (unsigned)(sx + dx_o) < 64u;
        const unsigned short* ab_o = catb + (sx + dx_o) * 1024 + ic_o;
        const unsigned short* wb_o = wt + ((size_t)tap_o << 19) +
                                     (size_t)(ocb + sx) * 1024 + ic_o + icsw;
        const int tap_n = ktn >> 4;
        const int dy_n = tap_n / 3 - 1;
        const int dx_n = tap_n % 3 - 1;
        const int ic_n = (ktn & 15) << 6;
        const bool xok_n = (unsigned)(sx + dx_n) < 64u;
        const unsigned short* ab_n = catb + (sx + dx_n) * 1024 + ic_n;
        const unsigned short* wb_n = wt + ((size_t)tap_n << 19) +
                                     (size_t)(ocb + sx) * 1024 + ic_n + icsw;
        READ_AF(0, 0) READ_BF(0, 0)
        STAGE_A(1, 0, dy_o, xok_o, ab_o);
        SYNC_PHASE(4)
        MFMA_Q(0, 0)
        READ_BF(0, 1)
        STAGE_B(1, 0, wb_o);
        SYNC_PHASE(4)
        MFMA_Q(0, 1)
        READ_AF(0, 1) READ_BF(0, 0)
        STAGE_B(1, 1, wb_o);
        SYNC_PHASE(6)
        MFMA_Q(1, 0)
        READ_BF(0, 1)
        STAGE_A(1, 1, dy_o, xok_o, ab_o);
        SYNC_PHASE(4)
        MFMA_Q(1, 1)
        READ_AF(1, 0) READ_BF(1, 0)
        STAGE_A(0, 0, dy_n, xok_n, ab_n);
        SYNC_PHASE(4)
        MFMA_Q(0, 0)
        READ_BF(1, 1)
        STAGE_B(0, 0, wb_n);
        SYNC_PHASE(4)
        MFMA_Q(0, 1)
        READ_AF(1, 1) READ_BF(1, 0)
        STAGE_B(0, 1, wb_n);
        SYNC_PHASE(6)
        MFMA_Q(1, 0)
        READ_BF(1, 1)
        STAGE_A(0, 1, dy_n, xok_n, ab_n);
        SYNC_PHASE(4)
        MFMA_Q(1, 1)
    }
    asm volatile("s_waitcnt vmcnt(0)" ::: "memory");

#pragma unroll
    for (int qn = 0; qn < 2; ++qn)
#pragma unroll
        for (int n = 0; n < 2; ++n) {
            const int oc = ocb + qn * 128 + wcol + n * 16 + l16;
            const float g = gamma[oc], bb = beta[oc];
#pragma unroll
            for (int qm = 0; qm < 2; ++qm)
#pragma unroll
                for (int m = 0; m < 4; ++m) {
                    const int P = qm * 128 + wrow + m * 16 + khalf * 4;
                    float4 o;
                    o.x = fmaxf(fmaf(acc[qm][qn][m][n][0], g, bb), 0.f);
                    o.y = fmaxf(fmaf(acc[qm][qn][m][n][1], g, bb), 0.f);
                    o.z = fmaxf(fmaf(acc[qm][qn][m][n][2], g, bb), 0.f);
                    o.w = fmaxf(fmaf(acc[qm][qn][m][n][3], g, bb), 0.f);
                    *(float4*)(out + ((size_t)(b * 512 + oc)) * 4096 + pix0 + P) = o;
                }
        }
#undef STAGE_A
#undef STAGE_B
#undef READ_AF
#undef READ_BF
#undef SYNC_PHASE
#undef MFMA_Q
}

// ---------------------------------------------------------------------------
extern "C" void kernel_launch(void* const* d_in, const int* in_sizes, int n_in,
                              void* d_out, int out_size, void* d_ws, size_t ws_size,
                              hipStream_t stream) {
    const float* x = (const float*)d_in[0];
    const float* dct = (const float*)d_in[1];
    const float* dm_w1 = (const float*)d_in[2];
    const float* dm_g = (const float*)d_in[3];
    const float* dm_b = (const float*)d_in[4];
    const float* dm_w2 = (const float*)d_in[5];
    const float* dm_b2 = (const float*)d_in[6];
    const float* fuse_w = (const float*)d_in[7];
    const float* fuse_b = (const float*)d_in[8];
    const float* gcn_w1 = (const float*)d_in[9];
    const float* gcn_w2 = (const float*)d_in[10];
    const float* bot_w = (const float*)d_in[11];
    const float* bot_g = (const float*)d_in[12];
    const float* bot_b = (const float*)d_in[13];

    float* y = (float*)d_out;
    float* out1 = y + (size_t)8 * 512 * 4096;
    // scratch in the y region (consumed by gcn/fuse_reduce before conv writes y)
    float* part = y;                     // 1,245,184 f32
    float* fpart = y + 1245184;          // 2,490,368 f32 (ends < 16.7M)

    char* ws = (char*)d_ws;
    const size_t CAT_BYTES = (size_t)8 * 4096 * 1024 * 2;     // 67108864
    const size_t WT_BYTES = (size_t)9 * 512 * 1024 * 2;       // 9437184
    const size_t PART_BYTES = (size_t)2048 * 152 * 4;         // (unused, kept for layout)
    const size_t L2_BYTES = (size_t)8 * 9728 * 4;             // 311296
    const size_t ZP_BYTES = 4096;
    if (ws_size < CAT_BYTES + WT_BYTES + PART_BYTES + L2_BYTES + ZP_BYTES) return;

    unsigned short* cat = (unsigned short*)ws;
    unsigned short* wt = (unsigned short*)(ws + CAT_BYTES);
    float* local2 = (float*)(ws + CAT_BYTES + WT_BYTES + PART_BYTES);
    unsigned short* zp = (unsigned short*)(ws + CAT_BYTES + WT_BYTES + PART_BYTES + L2_BYTES);

    hipMemsetAsync(zp, 0, ZP_BYTES, stream);
    front_kernel<<<dim3(512), dim3(256), 0, stream>>>(x, dct, dm_w1, dm_g, dm_b,
                                                      dm_w2, dm_b2, fuse_w,
                                                      part, fpart, cat);
    fuse_reduce<<<dim3(2432), dim3(256), 0, stream>>>(fpart, fuse_b, out1);
    gcn_kernel<<<dim3(8), dim3(256), 0, stream>>>(part, gcn_w1, gcn_w2, local2);
    repack_w<<<dim3(512), dim3(256), 0, stream>>>(bot_w, wt);
    attn_kernel<<<dim3(512), dim3(256), 0, stream>>>(x, local2, cat);
    conv_kernel<<<dim3(256), dim3(512), 0, stream>>>(cat, wt, zp, bot_g, bot_b, y);
}

// Round 6
// 410.062 us; speedup vs baseline: 2.2433x; 1.1072x over previous
//
#include <hip/hip_runtime.h>

// Problem constants
// B=8, C=512, H=W=64, HW=4096, NUM=64, CG=8, NC=19, OUT=512, ICAT=1024

typedef __attribute__((ext_vector_type(8))) unsigned short u16x8;
typedef __attribute__((ext_vector_type(8))) __bf16 bf16x8;
typedef __attribute__((ext_vector_type(4))) float f32x4;

__device__ inline unsigned short f2bf(float f) {
    unsigned int u = __float_as_uint(f);
    u += 0x7fffu + ((u >> 16) & 1u);
    return (unsigned short)(u >> 16);
}

__device__ __forceinline__ void gload16(unsigned short* lds, const unsigned short* g) {
    __builtin_amdgcn_global_load_lds(
        (const __attribute__((address_space(1))) unsigned int*)g,
        (__attribute__((address_space(3))) unsigned int*)lds, 16, 0, 0);
}

// ---------------------------------------------------------------------------
// Repack bot_w [512][1024][3][3] f32 -> wt[tap][oc][ic] bf16.
// ---------------------------------------------------------------------------
__global__ __launch_bounds__(256) void repack_w(const float* __restrict__ w,
                                                unsigned short* __restrict__ wt) {
    __shared__ float buf[9216];
    const int oc = blockIdx.x;  // 512
    const int tid = threadIdx.x;
    const float* src = w + (size_t)oc * 9216;
    for (int i = tid; i < 9216; i += 256) buf[i] = src[i];
    __syncthreads();
#pragma unroll
    for (int t = 0; t < 9; ++t) {
        for (int i = tid; i < 1024; i += 256)
            wt[((size_t)t * 512 + oc) * 1024 + i] = f2bf(buf[i * 9 + t]);
    }
}

// ---------------------------------------------------------------------------
// front: fused decoder_map + fuse-partial + local-partial + x->bf16 cat.
// ---------------------------------------------------------------------------
__global__ __launch_bounds__(256) void front_kernel(
    const float* __restrict__ x, const float* __restrict__ dct,
    const float* __restrict__ w1, const float* __restrict__ gamma,
    const float* __restrict__ beta, const float* __restrict__ w2,
    const float* __restrict__ b2, const float* __restrict__ fuse_w,
    float* __restrict__ part, float* __restrict__ fpart,
    unsigned short* __restrict__ cat) {
    __shared__ __align__(16) float fgs[8][260];
    __shared__ __align__(16) float fms[19][260];
    __shared__ float sw1[64], sw2[152], sb2[19], sg[8], sb[8], sfw[64];
    const int bid = blockIdx.x;
    const int sp = bid >> 7;
    const int b = (bid >> 4) & 7;
    const int ch = bid & 15;
    const int tid = threadIdx.x;
    if (tid < 64) { sw1[tid] = w1[tid]; sfw[tid] = fuse_w[tid]; }
    if (tid < 152) sw2[tid] = w2[tid];
    if (tid < 19) sb2[tid] = b2[tid];
    if (tid < 8) { sg[tid] = gamma[tid]; sb[tid] = beta[tid]; }
    __syncthreads();
    const int p = ch * 256 + tid;
    const int kk = tid >> 3, cc = tid & 7;
    float facc[19];
#pragma unroll
    for (int k = 0; k < 19; ++k) facc[k] = 0.f;
    for (int nn = 0; nn < 16; ++nn) {
        const int n = sp * 16 + nn;
        float fg[8];
        u16x8 xw;
#pragma unroll
        for (int c = 0; c < 8; ++c) {
            const float xv = x[((size_t)(b * 512 + n * 8 + c)) * 4096 + p];
            fg[c] = xv * dct[((size_t)(n * 8 + c)) * 4096 + p];
            xw[c] = f2bf(xv);
            fgs[c][tid] = fg[c];
        }
        *(u16x8*)(cat + ((size_t)(b * 4096) + p) * 1024 + n * 8) = xw;
        float h1[8];
#pragma unroll
        for (int d = 0; d < 8; ++d) {
            float s = 0.f;
#pragma unroll
            for (int c = 0; c < 8; ++c) s = fmaf(sw1[d * 8 + c], fg[c], s);
            h1[d] = fmaxf(fmaf(s, sg[d], sb[d]), 0.f);
        }
        const float fw = sfw[n];
#pragma unroll
        for (int k = 0; k < 19; ++k) {
            float s = sb2[k];
#pragma unroll
            for (int d = 0; d < 8; ++d) s = fmaf(sw2[k * 8 + d], h1[d], s);
            fms[k][tid] = s;
            facc[k] = fmaf(fw, s, facc[k]);
        }
        __syncthreads();
        if (tid < 152) {
            float accv = 0.f;
#pragma unroll 8
            for (int p4 = 0; p4 < 256; p4 += 4) {
                const float4 a = *(const float4*)&fms[kk][p4];
                const float4 g4 = *(const float4*)&fgs[cc][p4];
                accv += a.x * g4.x + a.y * g4.y + a.z * g4.z + a.w * g4.w;
            }
            part[((size_t)((b * 64 + n) * 16) + ch) * 152 + tid] = accv;
        }
        __syncthreads();
    }
#pragma unroll
    for (int k = 0; k < 19; ++k)
        fpart[((size_t)(sp * 8 + b) * 19 + k) * 4096 + p] = facc[k];
}

__global__ __launch_bounds__(256) void fuse_reduce(
    const float* __restrict__ fpart, const float* __restrict__ fuse_b,
    float* __restrict__ out1) {
    const int i = blockIdx.x * 256 + threadIdx.x;  // 622592 total
    float s = fuse_b[0];
#pragma unroll
    for (int sp = 0; sp < 4; ++sp) s += fpart[(size_t)sp * 622592 + i];
    out1[i] = s;
}

// ---------------------------------------------------------------------------
// GCN
// ---------------------------------------------------------------------------
__global__ __launch_bounds__(256) void gcn_kernel(
    const float* __restrict__ part, const float* __restrict__ w1,
    const float* __restrict__ w2, float* __restrict__ local2) {
    __shared__ float L[9728];
    __shared__ float R[9728];
    __shared__ float sw1[4096];
    __shared__ float sw2[64];
    const int b = blockIdx.x;
    const int tid = threadIdx.x;
    for (int i = tid; i < 4096; i += 256) sw1[i] = w1[i];
    if (tid < 64) sw2[tid] = w2[tid];
    for (int i = tid; i < 9728; i += 256) {
        int n = i / 152, t = i - n * 152;
        float s = 0.f;
#pragma unroll
        for (int ch = 0; ch < 16; ++ch)
            s += part[((size_t)((b * 64 + n) * 16) + ch) * 152 + t];
        L[i] = s;
    }
    __syncthreads();
    for (int i = tid; i < 9728; i += 256) {
        int m = i / 152, t = i - m * 152;
        float g = 0.f;
        for (int n = 0; n < 64; ++n) g = fmaf(sw1[m * 64 + n], L[n * 152 + t], g);
        R[i] = fmaxf(g + L[i], 0.f);
    }
    __syncthreads();
    for (int i = tid; i < 9728; i += 256) {
        int n = i / 152, t = i - n * 152;
        int k = t >> 3, d = t & 7;
        float s = 0.f;
#pragma unroll
        for (int c = 0; c < 8; ++c) s = fmaf(R[n * 152 + k * 8 + c], sw2[d * 8 + c], s);
        local2[(size_t)b * 9728 + i] = s;
    }
}

// ---------------------------------------------------------------------------
// attention: per (b,n): softmax(x@L^T)@L -> cat upper half bf16
// ---------------------------------------------------------------------------
__global__ __launch_bounds__(256) void attn_kernel(
    const float* __restrict__ x, const float* __restrict__ local2,
    unsigned short* __restrict__ cat) {
    __shared__ float L[152];
    const int bn = blockIdx.x;  // 512
    const int b = bn >> 6, n = bn & 63;
    const int tid = threadIdx.x;
    if (tid < 152) L[tid] = local2[(size_t)bn * 152 + tid];
    __syncthreads();
    for (int i = 0; i < 16; ++i) {
        const int p = i * 256 + tid;
        float xv[8];
#pragma unroll
        for (int c = 0; c < 8; ++c)
            xv[c] = x[((size_t)(b * 512 + n * 8 + c)) * 4096 + p];
        float lg[19];
        float mx = -1e30f;
#pragma unroll
        for (int k = 0; k < 19; ++k) {
            float s = 0.f;
#pragma unroll
            for (int c = 0; c < 8; ++c) s = fmaf(xv[c], L[k * 8 + c], s);
            lg[k] = s;
            mx = fmaxf(mx, s);
        }
        float se = 0.f;
#pragma unroll
        for (int k = 0; k < 19; ++k) {
            lg[k] = __expf(lg[k] - mx);
            se += lg[k];
        }
        const float inv = 1.f / se;
        float ov[8];
#pragma unroll
        for (int c = 0; c < 8; ++c) ov[c] = 0.f;
#pragma unroll
        for (int k = 0; k < 19; ++k) {
#pragma unroll
            for (int c = 0; c < 8; ++c) ov[c] = fmaf(lg[k], L[k * 8 + c], ov[c]);
        }
        u16x8 w;
#pragma unroll
        for (int c = 0; c < 8; ++c) w[c] = f2bf(ov[c] * inv);
        *(u16x8*)(cat + ((size_t)(b * 4096) + p) * 1024 + 512 + n * 8) = w;
    }
}

// ---------------------------------------------------------------------------
// conv 3x3 SAME implicit GEMM, ic-major K order with A-region reuse.
// Per 64-ic chunk: A-region (6 image rows x 64 x x 64 ic, 10 LDS slots:
// rows0/1 in-place recycled, rows2-5 parity-alternated) staged ONCE, then
// 9 taps run against it with (dy,dx) as LDS read offsets (x-halo zeroed via
// clamp+cndmask, y-halo from zero page).  B double-buffered per tap, halves
// staged 2 phase-pairs ahead.  4 phases/tap (qm0qn0,qm1qn0,qm1qn1,qm0qn1),
// ONE barrier/tap, counted vmcnt ledger (W0/W2 per tap, biased small).
// LDS: A 80KB + B 64KB = 144KB.
// ---------------------------------------------------------------------------
__global__ __launch_bounds__(512, 1) void conv_kernel(
    const unsigned short* __restrict__ cat, const unsigned short* __restrict__ wt,
    const unsigned short* __restrict__ zp,
    const float* __restrict__ gamma, const float* __restrict__ beta,
    float* __restrict__ out) {
    __shared__ __align__(16) unsigned short As[10 * 4096];  // 10 row-slots x 8KB
    __shared__ __align__(16) unsigned short Bs[2 * 16384];  // 2 slots x 32KB
    const int bid0 = blockIdx.x;                    // 256 blocks
    const int bid = (bid0 & 7) * 32 + (bid0 >> 3);  // XCD swizzle (bijective)
    const int mt = bid >> 1;                        // 128 M-tiles
    const int nt = bid & 1;                         // 2 N-tiles
    const int b = mt >> 4;
    const int pix0 = (mt & 15) * 256;
    const int y0 = (mt & 15) * 4;
    const int ocb = nt * 256;
    const int tid = threadIdx.x;
    const int w = tid >> 6;
    const int lane = tid & 63;
    const int l16 = lane & 15;
    const int khalf = lane >> 4;
    const int wr1 = w >> 2;           // wave row group 0/1
    const int wrow = wr1 * 64;
    const int wcol = (w & 3) * 32;
    const int sx = tid >> 3;                              // 0..63
    const int icsw = ((tid & 7) ^ ((tid >> 3) & 7)) * 8;  // pre-swizzled ic offset
    const unsigned short* zps = zp + icsw;
    const unsigned short* catb = cat + ((size_t)b * 4096) * 1024 + icsw;
    // swizzled column offsets (shorts) per dx in {-1,0,1}
    int colk[3][2];
#pragma unroll
    for (int d = 0; d < 3; ++d)
#pragma unroll
        for (int ks = 0; ks < 2; ++ks)
            colk[d][ks] = ((ks * 64 + khalf * 16) ^ (((l16 + d - 1) & 7) << 4)) >> 1;

    f32x4 acc[2][2][4][2];
#pragma unroll
    for (int qm = 0; qm < 2; ++qm)
#pragma unroll
        for (int qn = 0; qn < 2; ++qn)
#pragma unroll
            for (int m = 0; m < 4; ++m)
#pragma unroll
                for (int n = 0; n < 2; ++n)
#pragma unroll
                    for (int j = 0; j < 4; ++j) acc[qm][qn][m][n][j] = 0.f;

    bf16x8 af[4][2];
    bf16x8 bq[2][2];
    const bf16x8 zf = {};

#define AF_READ(QM, DY, DX)                                                        \
    {                                                                              \
        const int r_ = (QM) * 2 + wr1 + (DY) + 1;                                  \
        const int phys_ = (r_ < 2) ? r_ : r_ + 4 * cp;                             \
        const int rb_ = phys_ * 4096;                                              \
        _Pragma("unroll") for (int m_ = 0; m_ < 4; ++m_) {                         \
            const int xm_ = m_ * 16 + l16 + (DX);                                  \
            const int xc_ = ((DX) == 0) ? xm_ : min(max(xm_, 0), 63);              \
            const int ab_ = rb_ + xc_ * 64;                                        \
            _Pragma("unroll") for (int ks_ = 0; ks_ < 2; ++ks_)                    \
                af[m_][ks_] = *(const bf16x8*)(As + ab_ + colk[(DX) + 1][ks_]);    \
            if ((DX) == -1 && m_ == 0 && l16 == 0) { af[0][0] = zf; af[0][1] = zf; } \
            if ((DX) == 1 && m_ == 3 && l16 == 15) { af[3][0] = zf; af[3][1] = zf; } \
        }                                                                          \
    }

#define BQ_READ(SOFF, QN)                                                          \
    _Pragma("unroll") for (int n_ = 0; n_ < 2; ++n_)                               \
        _Pragma("unroll") for (int ks_ = 0; ks_ < 2; ++ks_)                        \
            bq[n_][ks_] = *(const bf16x8*)(Bs + (SOFF) +                           \
                ((QN) * 128 + wcol + n_ * 16 + l16) * 64 + colk[1][ks_]);

#define STAGE_BH(H, SWOFF, TAP, ICB)                                               \
    _Pragma("unroll") for (int j_ = 0; j_ < 2; ++j_) {                             \
        gload16(Bs + (SWOFF) + (H) * 8192 + (j_ * 512 + tid) * 8,                  \
                wt + (size_t)(TAP) * 524288 +                                      \
                    (size_t)(ocb + (H) * 128 + j_ * 64 + sx) * 1024 + (ICB) + icsw); \
    }

#define STAGE_AROW(R)                                                              \
    do {                                                                           \
        const int yy_ = y0 - 1 + (R);                                              \
        const int ph_ = ((R) < 2) ? (R) : (R) + 4 * cp1;                           \
        const unsigned short* s2_ = ((unsigned)yy_ < 64u)                          \
            ? catb + ((size_t)(yy_ * 64 + sx)) * 1024 + iccn : zps;                \
        gload16(As + ph_ * 4096 + tid * 8, s2_);                                   \
    } while (0)

#define MFMA16(QM, QN)                                                             \
    __builtin_amdgcn_s_setprio(1);                                                 \
    _Pragma("unroll") for (int m_ = 0; m_ < 4; ++m_)                               \
        _Pragma("unroll") for (int n_ = 0; n_ < 2; ++n_)                           \
            _Pragma("unroll") for (int ks_ = 0; ks_ < 2; ++ks_)                    \
                acc[QM][QN][m_][n_] = __builtin_amdgcn_mfma_f32_16x16x32_bf16(     \
                    af[m_][ks_], bq[n_][ks_], acc[QM][QN][m_][n_], 0, 0, 0);       \
    __builtin_amdgcn_s_setprio(0);

#define VWAIT(N)                                                                   \
    asm volatile("s_waitcnt vmcnt(" #N ")" ::: "memory");                          \
    __builtin_amdgcn_sched_barrier(0);

#define TAP_BODY(T, DY, DX, AROW, W0N, W2N)                                        \
    {                                                                              \
        const int s_ = (c + (T)) & 1;                                              \
        const int sr_ = s_ << 14;                                                  \
        const int sw_ = sr_ ^ 16384;                                               \
        const int tn_ = ((T) == 8) ? 0 : (T) + 1;                                  \
        const int icb_ = ((T) == 8) ? iccn : icc;                                  \
        /* ph0: qm0*qn0 */                                                         \
        VWAIT(W0N)                                                                 \
        __builtin_amdgcn_s_barrier();                                              \
        __builtin_amdgcn_sched_barrier(0);                                         \
        AF_READ(0, DY, DX)                                                         \
        BQ_READ(sr_, 0)                                                            \
        STAGE_BH(0, sw_, tn_, icb_)                                                \
        MFMA16(0, 0)                                                               \
        /* ph1: qm1*qn0 */                                                         \
        AF_READ(1, DY, DX)                                                         \
        if ((AROW) >= 0) STAGE_AROW(AROW);                                         \
        MFMA16(1, 0)                                                               \
        /* ph2: qm1*qn1 */                                                         \
        VWAIT(W2N)                                                                 \
        BQ_READ(sr_, 1)                                                            \
        STAGE_BH(1, sw_, tn_, icb_)                                                \
        MFMA16(1, 1)                                                               \
        /* ph3: qm0*qn1 */                                                         \
        AF_READ(0, DY, DX)                                                         \
        MFMA16(0, 1)                                                               \
    }

    // prologue: chunk 0 A-region (rows 0-5, parity 0) + B[0] both halves
    {
        const int cp1 = 0, iccn = 0;
#pragma unroll
        for (int r = 0; r < 6; ++r) STAGE_AROW(r);
    }
    STAGE_BH(0, 0, 0, 0)
    STAGE_BH(1, 0, 0, 0)

    for (int c = 0; c < 16; ++c) {
        const int cp = c & 1;
        const int cp1 = cp ^ 1;
        const int icc = c << 6;
        const int iccn = ((c + 1) & 15) << 6;
        TAP_BODY(0, -1, -1, -1, 2, 2)
        TAP_BODY(1, -1, 0, -1, 2, 2)
        TAP_BODY(2, -1, 1, -1, 2, 2)
        TAP_BODY(3, 0, -1, 0, 2, 3)
        TAP_BODY(4, 0, 0, 2, 3, 3)
        TAP_BODY(5, 0, 1, 3, 3, 3)
        TAP_BODY(6, 1, -1, 1, 3, 3)
        TAP_BODY(7, 1, 0, 4, 3, 3)
        TAP_BODY(8, 1, 1, 5, 3, 3)
    }
    asm volatile("s_waitcnt vmcnt(0)" ::: "memory");

    // epilogue: affine + relu, f32 out.  C/D: col(oc)=l16, row=khalf*4+j
#pragma unroll
    for (int qn = 0; qn < 2; ++qn)
#pragma unroll
        for (int n = 0; n < 2; ++n) {
            const int oc = ocb + qn * 128 + wcol + n * 16 + l16;
            const float g = gamma[oc], bb = beta[oc];
#pragma unroll
            for (int qm = 0; qm < 2; ++qm)
#pragma unroll
                for (int m = 0; m < 4; ++m) {
                    const int P = qm * 128 + wrow + m * 16 + khalf * 4;
                    float4 o;
                    o.x = fmaxf(fmaf(acc[qm][qn][m][n][0], g, bb), 0.f);
                    o.y = fmaxf(fmaf(acc[qm][qn][m][n][1], g, bb), 0.f);
                    o.z = fmaxf(fmaf(acc[qm][qn][m][n][2], g, bb), 0.f);
                    o.w = fmaxf(fmaf(acc[qm][qn][m][n][3], g, bb), 0.f);
                    *(float4*)(out + ((size_t)(b * 512 + oc)) * 4096 + pix0 + P) = o;
                }
        }
#undef AF_READ
#undef BQ_READ
#undef STAGE_BH
#undef STAGE_AROW
#undef MFMA16
#undef VWAIT
#undef TAP_BODY
}

// ---------------------------------------------------------------------------
extern "C" void kernel_launch(void* const* d_in, const int* in_sizes, int n_in,
                              void* d_out, int out_size, void* d_ws, size_t ws_size,
                              hipStream_t stream) {
    const float* x = (const float*)d_in[0];
    const float* dct = (const float*)d_in[1];
    const float* dm_w1 = (const float*)d_in[2];
    const float* dm_g = (const float*)d_in[3];
    const float* dm_b = (const float*)d_in[4];
    const float* dm_w2 = (const float*)d_in[5];
    const float* dm_b2 = (const float*)d_in[6];
    const float* fuse_w = (const float*)d_in[7];
    const float* fuse_b = (const float*)d_in[8];
    const float* gcn_w1 = (const float*)d_in[9];
    const float* gcn_w2 = (const float*)d_in[10];
    const float* bot_w = (const float*)d_in[11];
    const float* bot_g = (const float*)d_in[12];
    const float* bot_b = (const float*)d_in[13];

    float* y = (float*)d_out;
    float* out1 = y + (size_t)8 * 512 * 4096;
    // scratch in the y region (consumed by gcn/fuse_reduce before conv writes y)
    float* part = y;                     // 1,245,184 f32
    float* fpart = y + 1245184;          // 2,490,368 f32 (ends < 16.7M)

    char* ws = (char*)d_ws;
    const size_t CAT_BYTES = (size_t)8 * 4096 * 1024 * 2;     // 67108864
    const size_t WT_BYTES = (size_t)9 * 512 * 1024 * 2;       // 9437184
    const size_t PART_BYTES = (size_t)2048 * 152 * 4;         // (layout spacer)
    const size_t L2_BYTES = (size_t)8 * 9728 * 4;             // 311296
    const size_t ZP_BYTES = 4096;
    if (ws_size < CAT_BYTES + WT_BYTES + PART_BYTES + L2_BYTES + ZP_BYTES) return;

    unsigned short* cat = (unsigned short*)ws;
    unsigned short* wt = (unsigned short*)(ws + CAT_BYTES);
    float* local2 = (float*)(ws + CAT_BYTES + WT_BYTES + PART_BYTES);
    unsigned short* zp = (unsigned short*)(ws + CAT_BYTES + WT_BYTES + PART_BYTES + L2_BYTES);

    hipMemsetAsync(zp, 0, ZP_BYTES, stream);
    front_kernel<<<dim3(512), dim3(256), 0, stream>>>(x, dct, dm_w1, dm_g, dm_b,
                                                      dm_w2, dm_b2, fuse_w,
                                                      part, fpart, cat);
    fuse_reduce<<<dim3(2432), dim3(256), 0, stream>>>(fpart, fuse_b, out1);
    gcn_kernel<<<dim3(8), dim3(256), 0, stream>>>(part, gcn_w1, gcn_w2, local2);
    repack_w<<<dim3(512), dim3(256), 0, stream>>>(bot_w, wt);
    attn_kernel<<<dim3(512), dim3(256), 0, stream>>>(x, local2, cat);
    conv_kernel<<<dim3(256), dim3(512), 0, stream>>>(cat, wt, zp, bot_g, bot_b, y);
}